// Round 1
// baseline (1746.818 us; speedup 1.0000x reference)
//
#include <hip/hip_runtime.h>

#define Bq 4
#define Tq 16
#define Nq 4096
#define NFq 8
#define Hq 64
#define Eq 131072
#define Cq 13
#define Mq (Bq*Nq)

// ---------- helpers ----------
__device__ __forceinline__ float bf2f(unsigned short u) {
  return __uint_as_float(((unsigned int)u) << 16);
}
__device__ __forceinline__ unsigned short f2bf(float f) {
  unsigned int x = __float_as_uint(f);
  unsigned int r = x + 0x7fff + ((x >> 16) & 1);
  return (unsigned short)(r >> 16);
}
__device__ __forceinline__ float sigf(float x) { return 1.f / (1.f + __expf(-x)); }
__device__ __forceinline__ float tanh_f(float x) {
  float xc = fminf(fmaxf(x, -15.f), 15.f);
  float e = __expf(2.f * xc);
  return (e - 1.f) / (e + 1.f);
}

// ---------- K0: weight prep (transpose LSTM weights, combine biases) ----------
__global__ __launch_bounds__(256) void k_prep(
    const float* __restrict__ wih0, const float* __restrict__ whh0,
    const float* __restrict__ bih0, const float* __restrict__ bhh0,
    const float* __restrict__ wih1, const float* __restrict__ whh1,
    const float* __restrict__ bih1, const float* __restrict__ bhh1,
    float* __restrict__ wT) {
  int i = blockIdx.x * 256 + threadIdx.x;   // 0..16383
  int r = i >> 6, k = i & 63;
  int td = k * 256 + r;                      // transposed [k][row]
  wT[td]          = wih0[i];
  wT[16384 + td]  = whh0[i];
  wT[32768 + td]  = wih1[i];
  wT[49152 + td]  = whh1[i];
  if (i < 256) {
    wT[65536 + i] = bih0[i] + bhh0[i];
    wT[65792 + i] = bih1[i] + bhh1[i];
  }
}

// ---------- K1: spatial encoder: relu(nf@w1.T+b1)@w2.T+b2 -> bf16 ----------
__global__ __launch_bounds__(256) void k_enc(
    const float* __restrict__ nf, const float* __restrict__ w1,
    const float* __restrict__ b1, const float* __restrict__ w2,
    const float* __restrict__ b2, unsigned short* __restrict__ henc) {
  int row = blockIdx.x * 256 + threadIdx.x;  // 0..B*T*N-1
  const float4* nf4 = (const float4*)(nf + (size_t)row * NFq);
  float4 aa = nf4[0], bb4 = nf4[1];
  float x0 = aa.x, x1 = aa.y, x2v = aa.z, x3 = aa.w;
  float x4 = bb4.x, x5 = bb4.y, x6 = bb4.z, x7 = bb4.w;
  float h1[Hq];
  #pragma unroll 8
  for (int j = 0; j < Hq; ++j) {
    const float* wr = w1 + j * NFq;
    float acc = b1[j] + wr[0]*x0 + wr[1]*x1 + wr[2]*x2v + wr[3]*x3
                      + wr[4]*x4 + wr[5]*x5 + wr[6]*x6 + wr[7]*x7;
    h1[j] = fmaxf(acc, 0.f);
  }
  uint4* dst = (uint4*)(henc + (size_t)row * Hq);
  #pragma unroll 1
  for (int q4 = 0; q4 < 8; ++q4) {
    unsigned int pk[4];
    #pragma unroll
    for (int pp = 0; pp < 4; ++pp) {
      int j0 = q4 * 8 + pp * 2;
      float a0 = b2[j0], a1 = b2[j0 + 1];
      const float* wr0 = w2 + j0 * Hq;
      const float* wr1 = wr0 + Hq;
      #pragma unroll
      for (int k = 0; k < Hq; ++k) { a0 += wr0[k] * h1[k]; a1 += wr1[k] * h1[k]; }
      pk[pp] = (unsigned int)f2bf(a0) | ((unsigned int)f2bf(a1) << 16);
    }
    uint4 v; v.x = pk[0]; v.y = pk[1]; v.z = pk[2]; v.w = pk[3];
    dst[q4] = v;
  }
}

// ---------- K2: per-(t,node) in-degree count ----------
__global__ __launch_bounds__(256) void k_count(const int* __restrict__ ei,
                                               int* __restrict__ cnt) {
  int i = blockIdx.x * 256 + threadIdx.x;       // 0..T*E-1
  int t = i >> 17, e = i & (Eq - 1);
  int dst = ei[((t << 1) + 1) * Eq + e];
  atomicAdd(&cnt[(t << 12) + dst], 1);
}

// ---------- K3: per-t exclusive scan -> row_ptr ----------
__global__ __launch_bounds__(256) void k_scan(const int* __restrict__ cnt,
                                              int* __restrict__ rp) {
  int t = blockIdx.x, tid = threadIdx.x;
  __shared__ int part[256];
  int loc[16];
  int s = 0;
  #pragma unroll
  for (int j = 0; j < 16; ++j) { loc[j] = cnt[(t << 12) + tid * 16 + j]; s += loc[j]; }
  part[tid] = s;
  __syncthreads();
  if (tid == 0) {
    int run = 0;
    for (int i2 = 0; i2 < 256; ++i2) { int v = part[i2]; part[i2] = run; run += v; }
  }
  __syncthreads();
  int off = part[tid];
  #pragma unroll
  for (int j = 0; j < 16; ++j) { rp[t * (Nq + 1) + tid * 16 + j] = off; off += loc[j]; }
  if (tid == 255) rp[t * (Nq + 1) + Nq] = off;
}

// ---------- K4: scatter edges into CSR col ----------
__global__ __launch_bounds__(256) void k_scatter(const int* __restrict__ ei,
    const int* __restrict__ rp, int* __restrict__ fill, int* __restrict__ col) {
  int i = blockIdx.x * 256 + threadIdx.x;
  int t = i >> 17, e = i & (Eq - 1);
  int src = ei[(t << 1) * Eq + e];
  int dst = ei[((t << 1) + 1) * Eq + e];
  int pos = rp[t * (Nq + 1) + dst] + atomicAdd(&fill[(t << 12) + dst], 1);
  col[(t << 17) + pos] = src;
}

// ---------- K5: message passing (mean over in-edges, all 4 batches) ----------
__global__ __launch_bounds__(256) void k_mp(const unsigned short* __restrict__ henc,
    const int* __restrict__ rp, const int* __restrict__ col,
    unsigned short* __restrict__ hmp) {
  int lane = threadIdx.x & 63;
  int wv = (blockIdx.x * 256 + threadIdx.x) >> 6;  // global wave 0..4095
  int task0 = wv * 16;
  int t = task0 >> 12;
  int n0 = task0 & 4095;
  const int* rpt = rp + t * (Nq + 1);
  const int* colt = col + (t << 17);
  const unsigned short* ht = henc + t * 262144;    // (b=0,t) slab; batch stride 4194304
  for (int q = 0; q < 16; ++q) {
    int n = n0 + q;
    int e0 = rpt[n], e1 = rpt[n + 1];
    float a0 = 0.f, a1 = 0.f, a2 = 0.f, a3 = 0.f;
    for (int e = e0; e < e1; ++e) {
      int src = colt[e];
      const unsigned short* p = ht + src * 64 + lane;
      a0 += bf2f(p[0]);
      a1 += bf2f(p[4194304]);
      a2 += bf2f(p[8388608]);
      a3 += bf2f(p[12582912]);
    }
    int deg = e1 - e0;
    const unsigned short* pn = ht + n * 64 + lane;
    unsigned short* po = hmp + (pn - henc);
    if (deg > 0) {
      float scale = 0.5f / (float)deg;
      po[0]        = f2bf(bf2f(pn[0])        * 0.5f + a0 * scale);
      po[4194304]  = f2bf(bf2f(pn[4194304])  * 0.5f + a1 * scale);
      po[8388608]  = f2bf(bf2f(pn[8388608])  * 0.5f + a2 * scale);
      po[12582912] = f2bf(bf2f(pn[12582912]) * 0.5f + a3 * scale);
    } else {
      po[0] = pn[0]; po[4194304] = pn[4194304];
      po[8388608] = pn[8388608]; po[12582912] = pn[12582912];
    }
  }
}

// ---------- K6: fused 2-layer LSTM, persistent per 64 sequences ----------
// block = 1024 threads (16 waves); wave w owns channels [4w,4w+4); lane = sequence
__global__ __launch_bounds__(1024) void k_lstm(const unsigned short* __restrict__ hmp,
    const float* __restrict__ wT, unsigned short* __restrict__ x2) {
  __shared__ float xl[64][64];
  __shared__ float h0l[64][64];
  __shared__ float h1l[64][64];
  int tid = threadIdx.x;
  int lane = tid & 63;
  int wq = __builtin_amdgcn_readfirstlane(tid >> 6);   // 0..15
  int m0 = blockIdx.x << 6;
  int bb = m0 >> 12;
  int n0 = m0 & 4095;
  const float* wih0T = wT;
  const float* whh0T = wT + 16384;
  const float* wih1T = wT + 32768;
  const float* whh1T = wT + 49152;
  const float* bc0 = wT + 65536;
  const float* bc1 = wT + 65792;
  float c0[4] = {0.f, 0.f, 0.f, 0.f}, c1[4] = {0.f, 0.f, 0.f, 0.f};
  for (int i = tid; i < 4096; i += 1024) { (&h0l[0][0])[i] = 0.f; (&h1l[0][0])[i] = 0.f; }
  __syncthreads();
  int ss = tid >> 4, kc = (tid & 15) << 2;  // staging: thread loads 4 bf16
  const unsigned short* srcbase =
      hmp + ((size_t)(bb * 16) * 4096 + (size_t)(n0 + ss)) * 64 + kc;
  for (int t = 0; t < Tq; ++t) {
    {  // stage x_t transposed into xl[k][seq]
      uint2 p = *(const uint2*)(srcbase + t * 262144);
      xl[kc + 0][ss] = bf2f((unsigned short)(p.x & 0xffff));
      xl[kc + 1][ss] = bf2f((unsigned short)(p.x >> 16));
      xl[kc + 2][ss] = bf2f((unsigned short)(p.y & 0xffff));
      xl[kc + 3][ss] = bf2f((unsigned short)(p.y >> 16));
    }
    __syncthreads();
    // ---- layer 0 matmul: g = bc0 + x@wih0.T + h0@whh0.T
    float acc[4][4];
    #pragma unroll
    for (int g = 0; g < 4; ++g)
      #pragma unroll
      for (int j = 0; j < 4; ++j) acc[g][j] = bc0[g * 64 + wq * 4 + j];
    #pragma unroll 4
    for (int kk = 0; kk < 64; ++kk) {
      float xv = xl[kk][lane];
      const float* wr = wih0T + kk * 256 + wq * 4;
      #pragma unroll
      for (int g = 0; g < 4; ++g)
        #pragma unroll
        for (int j = 0; j < 4; ++j) acc[g][j] += wr[g * 64 + j] * xv;
      float hv = h0l[kk][lane];
      const float* wh = whh0T + kk * 256 + wq * 4;
      #pragma unroll
      for (int g = 0; g < 4; ++g)
        #pragma unroll
        for (int j = 0; j < 4; ++j) acc[g][j] += wh[g * 64 + j] * hv;
    }
    __syncthreads();
    #pragma unroll
    for (int j = 0; j < 4; ++j) {
      float ig = sigf(acc[0][j]);
      float fg = sigf(acc[1][j]);
      float gg = tanh_f(acc[2][j]);
      float og = sigf(acc[3][j]);
      float c = fg * c0[j] + ig * gg;
      c0[j] = c;
      h0l[wq * 4 + j][lane] = og * tanh_f(c);
    }
    __syncthreads();
    // ---- layer 1 matmul: g = bc1 + h0@wih1.T + h1@whh1.T
    #pragma unroll
    for (int g = 0; g < 4; ++g)
      #pragma unroll
      for (int j = 0; j < 4; ++j) acc[g][j] = bc1[g * 64 + wq * 4 + j];
    #pragma unroll 4
    for (int kk = 0; kk < 64; ++kk) {
      float xv = h0l[kk][lane];
      const float* wr = wih1T + kk * 256 + wq * 4;
      #pragma unroll
      for (int g = 0; g < 4; ++g)
        #pragma unroll
        for (int j = 0; j < 4; ++j) acc[g][j] += wr[g * 64 + j] * xv;
      float hv = h1l[kk][lane];
      const float* wh = whh1T + kk * 256 + wq * 4;
      #pragma unroll
      for (int g = 0; g < 4; ++g)
        #pragma unroll
        for (int j = 0; j < 4; ++j) acc[g][j] += wh[g * 64 + j] * hv;
    }
    __syncthreads();
    {
      float hn[4];
      #pragma unroll
      for (int j = 0; j < 4; ++j) {
        float ig = sigf(acc[0][j]);
        float fg = sigf(acc[1][j]);
        float gg = tanh_f(acc[2][j]);
        float og = sigf(acc[3][j]);
        float c = fg * c1[j] + ig * gg;
        c1[j] = c;
        hn[j] = og * tanh_f(c);
        h1l[wq * 4 + j][lane] = hn[j];
      }
      uint2 pv;
      pv.x = (unsigned int)f2bf(hn[0]) | ((unsigned int)f2bf(hn[1]) << 16);
      pv.y = (unsigned int)f2bf(hn[2]) | ((unsigned int)f2bf(hn[3]) << 16);
      *(uint2*)(x2 + ((size_t)(m0 + lane)) * (Tq * Hq) + t * Hq + wq * 4) = pv;
    }
    __syncthreads();
  }
}

// ---------- K7: attention (last-query only) + output MLP ----------
// block = 128 threads, 8 sequences; thread = (s, t)
__global__ __launch_bounds__(128) void k_attn(const unsigned short* __restrict__ x2,
    const float* __restrict__ aw, const float* __restrict__ ab,
    const float* __restrict__ ow, const float* __restrict__ ob,
    const float* __restrict__ pw1, const float* __restrict__ pb1,
    const float* __restrict__ pw2, const float* __restrict__ pb2,
    const float* __restrict__ pw3, const float* __restrict__ pb3,
    float* __restrict__ outp) {
  __shared__ __align__(16) char smem[40064];
  unsigned short* k_l = (unsigned short*)smem;          // [8][16][66]
  unsigned short* v_l = k_l + 8448;                     // [8][16][66]
  float* q_l = (float*)(smem + 33792);                  // [8][68]  (reused as fh)
  float* s_l = q_l + 544;                               // [8][4][16]
  float* o_l = s_l + 512;                               // [8][64]  (reused as z2)
  float* z1_l = (float*)smem;                           // [8][128] after kv dead
  float* z2_l = o_l;
  int tid = threadIdx.x;
  int s = tid >> 4, tt = tid & 15;
  int m = (blockIdx.x << 3) + s;
  // ---- phase 1: q (4 channels of row 15), then k/v for row tt
  {
    float xq[64];
    const uint4* xr = (const uint4*)(x2 + (size_t)m * 1024 + 15 * 64);
    #pragma unroll
    for (int q8 = 0; q8 < 8; ++q8) {
      uint4 p = xr[q8];
      unsigned int w_[4] = {p.x, p.y, p.z, p.w};
      #pragma unroll
      for (int j = 0; j < 4; ++j) {
        xq[q8 * 8 + j * 2]     = bf2f((unsigned short)(w_[j] & 0xffff));
        xq[q8 * 8 + j * 2 + 1] = bf2f((unsigned short)(w_[j] >> 16));
      }
    }
    #pragma unroll
    for (int c = 0; c < 4; ++c) {
      int ch = tt * 4 + c;
      const float* wr = aw + ch * 64;
      float acc = ab[ch];
      #pragma unroll
      for (int kk = 0; kk < 64; ++kk) acc += wr[kk] * xq[kk];
      q_l[s * 68 + ch] = acc * 0.25f;   // fold 1/sqrt(16)
    }
    float xv2[64];
    const uint4* xr2 = (const uint4*)(x2 + (size_t)m * 1024 + tt * 64);
    #pragma unroll
    for (int q8 = 0; q8 < 8; ++q8) {
      uint4 p = xr2[q8];
      unsigned int w_[4] = {p.x, p.y, p.z, p.w};
      #pragma unroll
      for (int j = 0; j < 4; ++j) {
        xv2[q8 * 8 + j * 2]     = bf2f((unsigned short)(w_[j] & 0xffff));
        xv2[q8 * 8 + j * 2 + 1] = bf2f((unsigned short)(w_[j] >> 16));
      }
    }
    #pragma unroll 2
    for (int ch = 0; ch < 64; ++ch) {
      const float* wk = aw + (64 + ch) * 64;
      const float* wv = aw + (128 + ch) * 64;
      float akc = ab[64 + ch], avc = ab[128 + ch];
      #pragma unroll
      for (int kk = 0; kk < 64; ++kk) { akc += wk[kk] * xv2[kk]; avc += wv[kk] * xv2[kk]; }
      k_l[(s * 16 + tt) * 66 + ch] = f2bf(akc);
      v_l[(s * 16 + tt) * 66 + ch] = f2bf(avc);
    }
  }
  __syncthreads();
  // ---- phase 2a: scores
  #pragma unroll
  for (int h = 0; h < 4; ++h) {
    float acc = 0.f;
    #pragma unroll
    for (int d = 0; d < 16; ++d)
      acc += q_l[s * 68 + h * 16 + d] * bf2f(k_l[(s * 16 + tt) * 66 + h * 16 + d]);
    s_l[s * 64 + h * 16 + tt] = acc;
  }
  __syncthreads();
  // ---- phase 2b: softmax over t (thread = (s, head))
  if (tid < 32) {
    int s2 = tid >> 2, h = tid & 3;
    float* row = s_l + s2 * 64 + h * 16;
    float mx = row[0];
    #pragma unroll
    for (int j = 1; j < 16; ++j) mx = fmaxf(mx, row[j]);
    float sum = 0.f;
    float ev[16];
    #pragma unroll
    for (int j = 0; j < 16; ++j) { ev[j] = __expf(row[j] - mx); sum += ev[j]; }
    float inv = 1.f / sum;
    #pragma unroll
    for (int j = 0; j < 16; ++j) row[j] = ev[j] * inv;
  }
  __syncthreads();
  // ---- phase 2c: o = attn @ v (thread = (s, 4-channel group))
  {
    int g = tid & 15;
    #pragma unroll
    for (int c = 0; c < 4; ++c) {
      int ch = g * 4 + c;
      int h = ch >> 4;
      float acc = 0.f;
      #pragma unroll
      for (int t2 = 0; t2 < 16; ++t2)
        acc += s_l[s * 64 + h * 16 + t2] * bf2f(v_l[(s * 16 + t2) * 66 + ch]);
      o_l[s * 64 + ch] = acc;
    }
  }
  __syncthreads();
  // ---- phase 3: out projection -> fh (q_l region)
  {
    int g = tid & 15;
    #pragma unroll
    for (int c = 0; c < 4; ++c) {
      int ch = g * 4 + c;
      const float* wr = ow + ch * 64;
      float acc = ob[ch];
      #pragma unroll
      for (int kk = 0; kk < 64; ++kk) acc += wr[kk] * o_l[s * 64 + kk];
      q_l[s * 68 + ch] = acc;
    }
  }
  __syncthreads();
  // ---- phase 4: z1 = relu(fh @ pw1.T + pb1)  (128 ch)
  {
    int g = tid & 15;
    #pragma unroll
    for (int c = 0; c < 8; ++c) {
      int ch = g * 8 + c;
      const float* wr = pw1 + ch * 64;
      float acc = pb1[ch];
      #pragma unroll
      for (int kk = 0; kk < 64; ++kk) acc += wr[kk] * q_l[s * 68 + kk];
      z1_l[s * 128 + ch] = fmaxf(acc, 0.f);
    }
  }
  __syncthreads();
  // ---- phase 5: z2 = relu(z1 @ pw2.T + pb2)  (64 ch)
  {
    int g = tid & 15;
    #pragma unroll
    for (int c = 0; c < 4; ++c) {
      int ch = g * 4 + c;
      const float* wr = pw2 + ch * 128;
      float acc = pb2[ch];
      #pragma unroll
      for (int kk = 0; kk < 128; ++kk) acc += wr[kk] * z1_l[s * 128 + kk];
      z2_l[s * 64 + ch] = fmaxf(acc, 0.f);
    }
  }
  __syncthreads();
  // ---- phase 6: logits
  {
    int c = tid & 15;
    if (c < 13) {
      const float* wr = pw3 + c * 64;
      float acc = pb3[c];
      #pragma unroll
      for (int kk = 0; kk < 64; ++kk) acc += wr[kk] * z2_l[s * 64 + kk];
      outp[m * 13 + c] = acc;
    }
  }
}

extern "C" void kernel_launch(void* const* d_in, const int* in_sizes, int n_in,
                              void* d_out, int out_size, void* d_ws, size_t ws_size,
                              hipStream_t stream) {
  (void)in_sizes; (void)n_in; (void)out_size; (void)ws_size;
  const float* nf   = (const float*)d_in[0];
  const int*   ei   = (const int*)d_in[1];
  const float* sw1  = (const float*)d_in[2];
  const float* sb1  = (const float*)d_in[3];
  const float* sw2  = (const float*)d_in[4];
  const float* sb2  = (const float*)d_in[5];
  const float* wih0 = (const float*)d_in[6];
  const float* whh0 = (const float*)d_in[7];
  const float* bih0 = (const float*)d_in[8];
  const float* bhh0 = (const float*)d_in[9];
  const float* wih1 = (const float*)d_in[10];
  const float* whh1 = (const float*)d_in[11];
  const float* bih1 = (const float*)d_in[12];
  const float* bhh1 = (const float*)d_in[13];
  const float* aw   = (const float*)d_in[14];
  const float* ab   = (const float*)d_in[15];
  const float* ow   = (const float*)d_in[16];
  const float* ob   = (const float*)d_in[17];
  const float* pw1  = (const float*)d_in[18];
  const float* pb1  = (const float*)d_in[19];
  const float* pw2  = (const float*)d_in[20];
  const float* pb2  = (const float*)d_in[21];
  const float* pw3  = (const float*)d_in[22];
  const float* pb3  = (const float*)d_in[23];

  char* ws = (char*)d_ws;
  float* wT = (float*)ws;                                   //   0     .. 264 KB
  int* cnt  = (int*)(ws + 524288);                          // 512 KB  (256 KB)
  int* fill = (int*)(ws + 786432);                          // 768 KB  (256 KB)
  int* rp   = (int*)(ws + 1048576);                         //   1 MB  (~256 KB)
  int* col  = (int*)(ws + 1572864);                         // 1.5 MB  (8 MB)
  unsigned short* henc = (unsigned short*)(ws + 10485760);  //  10 MB  (32 MB)
  unsigned short* hmp  = (unsigned short*)(ws + 44040192);  //  42 MB  (32 MB)
  unsigned short* x2   = henc;   // alias: henc dead after k_mp
  float* outp = (float*)d_out;

  hipMemsetAsync(ws + 524288, 0, 524288, stream);           // zero cnt+fill
  k_prep<<<64, 256, 0, stream>>>(wih0, whh0, bih0, bhh0, wih1, whh1, bih1, bhh1, wT);
  k_enc<<<1024, 256, 0, stream>>>(nf, sw1, sb1, sw2, sb2, henc);
  k_count<<<8192, 256, 0, stream>>>(ei, cnt);
  k_scan<<<16, 256, 0, stream>>>(cnt, rp);
  k_scatter<<<8192, 256, 0, stream>>>(ei, rp, fill, col);
  k_mp<<<1024, 256, 0, stream>>>(henc, rp, col, hmp);
  k_lstm<<<256, 1024, 0, stream>>>(hmp, wT, x2);
  k_attn<<<2048, 128, 0, stream>>>(x2, aw, ab, ow, ob, pw1, pb1, pw2, pb2, pw3, pb3, outp);
}

// Round 2
// 1003.478 us; speedup vs baseline: 1.7408x; 1.7408x over previous
//
#include <hip/hip_runtime.h>

#define Bq 4
#define Tq 16
#define Nq 4096
#define NFq 8
#define Hq 64
#define Eq 131072
#define Cq 13
#define Mq (Bq*Nq)

// ---------- helpers ----------
__device__ __forceinline__ float bf2f(unsigned short u) {
  return __uint_as_float(((unsigned int)u) << 16);
}
__device__ __forceinline__ unsigned short f2bf(float f) {
  unsigned int x = __float_as_uint(f);
  unsigned int r = x + 0x7fff + ((x >> 16) & 1);
  return (unsigned short)(r >> 16);
}
__device__ __forceinline__ float sigf(float x) { return 1.f / (1.f + __expf(-x)); }
__device__ __forceinline__ float tanh_f(float x) {
  float xc = fminf(fmaxf(x, -15.f), 15.f);
  float e = __expf(2.f * xc);
  return (e - 1.f) / (e + 1.f);
}

// wT float offsets
#define O_WIH0 0
#define O_WHH0 16384
#define O_WIH1 32768
#define O_WHH1 49152
#define O_BC0  65536
#define O_BC1  65792
#define O_AQT  66048
#define O_QB   70144
#define O_WVT  70208
#define O_VB   74304
#define O_OWT  74368
#define O_P1T  78464
#define O_P2T  86656
#define O_P3T  94848

// ---------- K0: LSTM weight transpose + bias combine ----------
__global__ __launch_bounds__(256) void k_prep(
    const float* __restrict__ wih0, const float* __restrict__ whh0,
    const float* __restrict__ bih0, const float* __restrict__ bhh0,
    const float* __restrict__ wih1, const float* __restrict__ whh1,
    const float* __restrict__ bih1, const float* __restrict__ bhh1,
    float* __restrict__ wT) {
  int i = blockIdx.x * 256 + threadIdx.x;   // 0..16383
  int r = i >> 6, k = i & 63;
  int td = k * 256 + r;                      // transposed [k][row]
  wT[O_WIH0 + td] = wih0[i];
  wT[O_WHH0 + td] = whh0[i];
  wT[O_WIH1 + td] = wih1[i];
  wT[O_WHH1 + td] = whh1[i];
  if (i < 256) {
    wT[O_BC0 + i] = bih0[i] + bhh0[i];
    wT[O_BC1 + i] = bih1[i] + bhh1[i];
  }
}

// ---------- K0b: attention/MLP weight transposes ----------
__global__ __launch_bounds__(256) void k_prep2(
    const float* __restrict__ aw, const float* __restrict__ ab,
    const float* __restrict__ ow,
    const float* __restrict__ pw1, const float* __restrict__ pw2,
    const float* __restrict__ pw3, float* __restrict__ wT) {
  int i = blockIdx.x * 256 + threadIdx.x;   // 0..8191
  if (i < 4096) {
    int k = i >> 6, ch = i & 63;
    wT[O_AQT + i] = 0.25f * aw[ch * 64 + k];          // q rows, fold 1/sqrt(hd)
    wT[O_WVT + i] = aw[(128 + ch) * 64 + k];          // v rows
    wT[O_OWT + i] = ow[ch * 64 + k];
  }
  if (i < 64) {
    wT[O_QB + i] = 0.25f * ab[i];
    wT[O_VB + i] = ab[128 + i];
  }
  {  // pw1T [k<64][ch<128]
    int k = i >> 7, ch = i & 127;
    wT[O_P1T + i] = pw1[ch * 64 + k];
  }
  {  // pw2T [k<128][ch<64]
    int k = i >> 6, ch = i & 63;
    wT[O_P2T + i] = pw2[ch * 128 + k];
  }
  if (i < 1024) {  // pw3T [k<64][c<16]
    int k = i >> 4, c = i & 15;
    wT[O_P3T + i] = (c < 13) ? pw3[c * 64 + k] : 0.f;
  }
}

// ---------- K1: spatial encoder ----------
__global__ __launch_bounds__(256) void k_enc(
    const float* __restrict__ nf, const float* __restrict__ w1,
    const float* __restrict__ b1, const float* __restrict__ w2,
    const float* __restrict__ b2, unsigned short* __restrict__ henc) {
  int row = blockIdx.x * 256 + threadIdx.x;  // 0..B*T*N-1
  const float4* nf4 = (const float4*)(nf + (size_t)row * NFq);
  float4 aa = nf4[0], bb4 = nf4[1];
  float x0 = aa.x, x1 = aa.y, x2v = aa.z, x3 = aa.w;
  float x4 = bb4.x, x5 = bb4.y, x6 = bb4.z, x7 = bb4.w;
  float h1[Hq];
  #pragma unroll 8
  for (int j = 0; j < Hq; ++j) {
    const float* wr = w1 + j * NFq;
    float acc = b1[j] + wr[0]*x0 + wr[1]*x1 + wr[2]*x2v + wr[3]*x3
                      + wr[4]*x4 + wr[5]*x5 + wr[6]*x6 + wr[7]*x7;
    h1[j] = fmaxf(acc, 0.f);
  }
  uint4* dst = (uint4*)(henc + (size_t)row * Hq);
  #pragma unroll 1
  for (int q4 = 0; q4 < 8; ++q4) {
    unsigned int pk[4];
    #pragma unroll
    for (int pp = 0; pp < 4; ++pp) {
      int j0 = q4 * 8 + pp * 2;
      float a0 = b2[j0], a1 = b2[j0 + 1];
      const float* wr0 = w2 + j0 * Hq;
      const float* wr1 = wr0 + Hq;
      #pragma unroll
      for (int k = 0; k < Hq; ++k) { a0 += wr0[k] * h1[k]; a1 += wr1[k] * h1[k]; }
      pk[pp] = (unsigned int)f2bf(a0) | ((unsigned int)f2bf(a1) << 16);
    }
    uint4 v; v.x = pk[0]; v.y = pk[1]; v.z = pk[2]; v.w = pk[3];
    dst[q4] = v;
  }
}

// ---------- K2..K4: CSR build ----------
__global__ __launch_bounds__(256) void k_count(const int* __restrict__ ei,
                                               int* __restrict__ cnt) {
  int i = blockIdx.x * 256 + threadIdx.x;
  int t = i >> 17, e = i & (Eq - 1);
  int dst = ei[((t << 1) + 1) * Eq + e];
  atomicAdd(&cnt[(t << 12) + dst], 1);
}

__global__ __launch_bounds__(256) void k_scan(const int* __restrict__ cnt,
                                              int* __restrict__ rp) {
  int t = blockIdx.x, tid = threadIdx.x;
  __shared__ int part[256];
  int loc[16];
  int s = 0;
  #pragma unroll
  for (int j = 0; j < 16; ++j) { loc[j] = cnt[(t << 12) + tid * 16 + j]; s += loc[j]; }
  part[tid] = s;
  __syncthreads();
  if (tid == 0) {
    int run = 0;
    for (int i2 = 0; i2 < 256; ++i2) { int v = part[i2]; part[i2] = run; run += v; }
  }
  __syncthreads();
  int off = part[tid];
  #pragma unroll
  for (int j = 0; j < 16; ++j) { rp[t * (Nq + 1) + tid * 16 + j] = off; off += loc[j]; }
  if (tid == 255) rp[t * (Nq + 1) + Nq] = off;
}

__global__ __launch_bounds__(256) void k_scatter(const int* __restrict__ ei,
    const int* __restrict__ rp, int* __restrict__ fill, int* __restrict__ col) {
  int i = blockIdx.x * 256 + threadIdx.x;
  int t = i >> 17, e = i & (Eq - 1);
  int src = ei[(t << 1) * Eq + e];
  int dst = ei[((t << 1) + 1) * Eq + e];
  int pos = rp[t * (Nq + 1) + dst] + atomicAdd(&fill[(t << 12) + dst], 1);
  col[(t << 17) + pos] = src;
}

// ---------- K5: message passing; wave = (t,n) task, lane = (b, 4-ch chunk) ----------
__global__ __launch_bounds__(256) void k_mp(const unsigned short* __restrict__ henc,
    const int* __restrict__ rp, const int* __restrict__ col,
    unsigned short* __restrict__ hmp) {
  int lane = threadIdx.x & 63;
  int task = blockIdx.x * 4 + __builtin_amdgcn_readfirstlane(threadIdx.x >> 6);
  int t = task >> 12, n = task & 4095;
  const int* rpt = rp + t * (Nq + 1);
  const int* colt = col + (t << 17);
  int e0 = rpt[n], e1 = rpt[n + 1];
  const unsigned short* ht = henc + t * 262144;      // t-slab; batch stride 4194304
  size_t loff = (size_t)(lane >> 4) * 4194304 + ((lane & 15) << 2);
  float a0 = 0.f, a1 = 0.f, a2 = 0.f, a3 = 0.f;
  for (int e = e0; e < e1; ++e) {
    int src = colt[e];
    uint2 p = *(const uint2*)(ht + loff + src * 64);
    a0 += bf2f((unsigned short)(p.x & 0xffff));
    a1 += bf2f((unsigned short)(p.x >> 16));
    a2 += bf2f((unsigned short)(p.y & 0xffff));
    a3 += bf2f((unsigned short)(p.y >> 16));
  }
  uint2 ps = *(const uint2*)(ht + loff + n * 64);
  unsigned short* po = hmp + t * 262144 + loff + n * 64;
  int deg = e1 - e0;
  uint2 out;
  if (deg > 0) {
    float sc = 0.5f / (float)deg;
    float s0 = bf2f((unsigned short)(ps.x & 0xffff)) * 0.5f + a0 * sc;
    float s1 = bf2f((unsigned short)(ps.x >> 16))    * 0.5f + a1 * sc;
    float s2 = bf2f((unsigned short)(ps.y & 0xffff)) * 0.5f + a2 * sc;
    float s3 = bf2f((unsigned short)(ps.y >> 16))    * 0.5f + a3 * sc;
    out.x = (unsigned int)f2bf(s0) | ((unsigned int)f2bf(s1) << 16);
    out.y = (unsigned int)f2bf(s2) | ((unsigned int)f2bf(s3) << 16);
  } else {
    out = ps;
  }
  *(uint2*)po = out;
}

// ---------- K6: fused 2-layer LSTM (unchanged, known-good) ----------
__global__ __launch_bounds__(1024) void k_lstm(const unsigned short* __restrict__ hmp,
    const float* __restrict__ wT, unsigned short* __restrict__ x2) {
  __shared__ float xl[64][64];
  __shared__ float h0l[64][64];
  __shared__ float h1l[64][64];
  int tid = threadIdx.x;
  int lane = tid & 63;
  int wq = __builtin_amdgcn_readfirstlane(tid >> 6);   // 0..15
  int m0 = blockIdx.x << 6;
  int bb = m0 >> 12;
  int n0 = m0 & 4095;
  const float* wih0T = wT + O_WIH0;
  const float* whh0T = wT + O_WHH0;
  const float* wih1T = wT + O_WIH1;
  const float* whh1T = wT + O_WHH1;
  const float* bc0 = wT + O_BC0;
  const float* bc1 = wT + O_BC1;
  float c0[4] = {0.f, 0.f, 0.f, 0.f}, c1[4] = {0.f, 0.f, 0.f, 0.f};
  for (int i = tid; i < 4096; i += 1024) { (&h0l[0][0])[i] = 0.f; (&h1l[0][0])[i] = 0.f; }
  __syncthreads();
  int ss = tid >> 4, kc = (tid & 15) << 2;
  const unsigned short* srcbase =
      hmp + ((size_t)(bb * 16) * 4096 + (size_t)(n0 + ss)) * 64 + kc;
  for (int t = 0; t < Tq; ++t) {
    {
      uint2 p = *(const uint2*)(srcbase + t * 262144);
      xl[kc + 0][ss] = bf2f((unsigned short)(p.x & 0xffff));
      xl[kc + 1][ss] = bf2f((unsigned short)(p.x >> 16));
      xl[kc + 2][ss] = bf2f((unsigned short)(p.y & 0xffff));
      xl[kc + 3][ss] = bf2f((unsigned short)(p.y >> 16));
    }
    __syncthreads();
    float acc[4][4];
    #pragma unroll
    for (int g = 0; g < 4; ++g)
      #pragma unroll
      for (int j = 0; j < 4; ++j) acc[g][j] = bc0[g * 64 + wq * 4 + j];
    #pragma unroll 4
    for (int kk = 0; kk < 64; ++kk) {
      float xv = xl[kk][lane];
      const float* wr = wih0T + kk * 256 + wq * 4;
      #pragma unroll
      for (int g = 0; g < 4; ++g)
        #pragma unroll
        for (int j = 0; j < 4; ++j) acc[g][j] += wr[g * 64 + j] * xv;
      float hv = h0l[kk][lane];
      const float* wh = whh0T + kk * 256 + wq * 4;
      #pragma unroll
      for (int g = 0; g < 4; ++g)
        #pragma unroll
        for (int j = 0; j < 4; ++j) acc[g][j] += wh[g * 64 + j] * hv;
    }
    __syncthreads();
    #pragma unroll
    for (int j = 0; j < 4; ++j) {
      float ig = sigf(acc[0][j]);
      float fg = sigf(acc[1][j]);
      float gg = tanh_f(acc[2][j]);
      float og = sigf(acc[3][j]);
      float c = fg * c0[j] + ig * gg;
      c0[j] = c;
      h0l[wq * 4 + j][lane] = og * tanh_f(c);
    }
    __syncthreads();
    #pragma unroll
    for (int g = 0; g < 4; ++g)
      #pragma unroll
      for (int j = 0; j < 4; ++j) acc[g][j] = bc1[g * 64 + wq * 4 + j];
    #pragma unroll 4
    for (int kk = 0; kk < 64; ++kk) {
      float xv = h0l[kk][lane];
      const float* wr = wih1T + kk * 256 + wq * 4;
      #pragma unroll
      for (int g = 0; g < 4; ++g)
        #pragma unroll
        for (int j = 0; j < 4; ++j) acc[g][j] += wr[g * 64 + j] * xv;
      float hv = h1l[kk][lane];
      const float* wh = whh1T + kk * 256 + wq * 4;
      #pragma unroll
      for (int g = 0; g < 4; ++g)
        #pragma unroll
        for (int j = 0; j < 4; ++j) acc[g][j] += wh[g * 64 + j] * hv;
    }
    __syncthreads();
    {
      float hn[4];
      #pragma unroll
      for (int j = 0; j < 4; ++j) {
        float ig = sigf(acc[0][j]);
        float fg = sigf(acc[1][j]);
        float gg = tanh_f(acc[2][j]);
        float og = sigf(acc[3][j]);
        float c = fg * c1[j] + ig * gg;
        c1[j] = c;
        hn[j] = og * tanh_f(c);
        h1l[wq * 4 + j][lane] = hn[j];
      }
      uint2 pv;
      pv.x = (unsigned int)f2bf(hn[0]) | ((unsigned int)f2bf(hn[1]) << 16);
      pv.y = (unsigned int)f2bf(hn[2]) | ((unsigned int)f2bf(hn[3]) << 16);
      *(uint2*)(x2 + ((size_t)(m0 + lane)) * (Tq * Hq) + t * Hq + wq * 4) = pv;
    }
    __syncthreads();
  }
}

// ---------- K7: attention (folded) + MLP; wave = sequence, lane = channel ----------
// LDS per-wave region (floats): xl[16][65]@0, ql@1040, qkl[4][68]@1104,
// pl@1376, hbl[4][68]@1440, ol@1712, fl@1776, z1l@1840, z2l@1968  (2048 total)
__global__ __launch_bounds__(256) void k_attn(const unsigned short* __restrict__ x2,
    const float* __restrict__ wp, const float* __restrict__ aw,
    const float* __restrict__ obv, const float* __restrict__ pb1,
    const float* __restrict__ pb2, const float* __restrict__ pb3,
    float* __restrict__ outp) {
  __shared__ float smem[8192];
  int lane = threadIdx.x & 63;
  float* W = smem + ((threadIdx.x >> 6) << 11);
  int m = (blockIdx.x << 2) + (threadIdx.x >> 6);
  // --- A: stage x[t][ch] into LDS (f32, rows padded to 65)
  const uint4* xp = (const uint4*)(x2 + (size_t)m * 1024);
  #pragma unroll
  for (int u = 0; u < 2; ++u) {
    uint4 pv = xp[lane * 2 + u];
    int f0 = (lane * 2 + u) * 8;
    unsigned int ww[4] = {pv.x, pv.y, pv.z, pv.w};
    #pragma unroll
    for (int j = 0; j < 4; ++j) {
      int f = f0 + j * 2;
      int t = f >> 6, ch = f & 63;
      W[t * 65 + ch]     = bf2f((unsigned short)(ww[j] & 0xffff));
      W[t * 65 + ch + 1] = bf2f((unsigned short)(ww[j] >> 16));
    }
  }
  __syncthreads();
  // --- B: q[ch] = qb[ch] + aqT^T x15   (scale folded)
  {
    float qacc = wp[O_QB + lane];
    const float* aqT = wp + O_AQT;
    #pragma unroll 4
    for (int kk = 0; kk < 64; ++kk) qacc += aqT[kk * 64 + lane] * W[15 * 65 + kk];
    W[1040 + lane] = qacc;
  }
  __syncthreads();
  // --- C: qk_h = Wk_h^T q_h  (Wk rows read coalesced straight from aw)
  #pragma unroll
  for (int h = 0; h < 4; ++h) {
    float a = 0.f;
    #pragma unroll 4
    for (int d = 0; d < 16; ++d) {
      float coef = W[1040 + h * 16 + d];
      a += aw[(64 + h * 16 + d) * 64 + lane] * coef;
    }
    W[1104 + h * 68 + lane] = a;
  }
  __syncthreads();
  // --- D: scores + softmax; lane = h*16 + t
  {
    int hh = lane >> 4, tt2 = lane & 15;
    float sc = 0.f;
    #pragma unroll 4
    for (int ch = 0; ch < 64; ++ch)
      sc += W[1104 + hh * 68 + ch] * W[tt2 * 65 + ch];
    float mx = sc;
    mx = fmaxf(mx, __shfl_xor(mx, 1));
    mx = fmaxf(mx, __shfl_xor(mx, 2));
    mx = fmaxf(mx, __shfl_xor(mx, 4));
    mx = fmaxf(mx, __shfl_xor(mx, 8));
    float e = __expf(sc - mx);
    float sum = e;
    sum += __shfl_xor(sum, 1);
    sum += __shfl_xor(sum, 2);
    sum += __shfl_xor(sum, 4);
    sum += __shfl_xor(sum, 8);
    W[1376 + lane] = e / sum;
  }
  __syncthreads();
  // --- E: hbar_h = sum_t p[h][t] * x_t
  {
    float hb[4] = {0.f, 0.f, 0.f, 0.f};
    for (int t = 0; t < 16; ++t) {
      float xv = W[t * 65 + lane];
      #pragma unroll
      for (int h = 0; h < 4; ++h) hb[h] += W[1376 + h * 16 + t] * xv;
    }
    #pragma unroll
    for (int h = 0; h < 4; ++h) W[1440 + h * 68 + lane] = hb[h];
  }
  __syncthreads();
  // --- F: o = Wv hbar_{h(ch)} + vb
  {
    const float* wvT = wp + O_WVT;
    float oacc = wp[O_VB + lane];
    int hsel = lane >> 4;
    #pragma unroll 4
    for (int k = 0; k < 64; ++k) oacc += wvT[k * 64 + lane] * W[1440 + hsel * 68 + k];
    W[1712 + lane] = oacc;
  }
  __syncthreads();
  // --- G: fh = ow o + ob
  {
    const float* owT = wp + O_OWT;
    float facc = obv[lane];
    #pragma unroll 4
    for (int k = 0; k < 64; ++k) facc += owT[k * 64 + lane] * W[1712 + k];
    W[1776 + lane] = facc;
  }
  __syncthreads();
  // --- H: z1 = relu(pw1 fh + pb1), 128 ch (2 per lane)
  {
    const float* p1T = wp + O_P1T;
    float a0 = pb1[lane], a1 = pb1[64 + lane];
    #pragma unroll 4
    for (int k = 0; k < 64; ++k) {
      float fv = W[1776 + k];
      a0 += p1T[k * 128 + lane] * fv;
      a1 += p1T[k * 128 + 64 + lane] * fv;
    }
    W[1840 + lane] = fmaxf(a0, 0.f);
    W[1904 + lane] = fmaxf(a1, 0.f);
  }
  __syncthreads();
  // --- I: z2 = relu(pw2 z1 + pb2)
  {
    const float* p2T = wp + O_P2T;
    float a2 = pb2[lane];
    #pragma unroll 4
    for (int k = 0; k < 128; ++k) a2 += p2T[k * 64 + lane] * W[1840 + k];
    W[1968 + lane] = fmaxf(a2, 0.f);
  }
  __syncthreads();
  // --- J: logits
  if (lane < 13) {
    const float* p3T = wp + O_P3T;
    float a3 = pb3[lane];
    #pragma unroll 4
    for (int k = 0; k < 64; ++k) a3 += p3T[k * 16 + lane] * W[1968 + k];
    outp[(size_t)m * 13 + lane] = a3;
  }
}

extern "C" void kernel_launch(void* const* d_in, const int* in_sizes, int n_in,
                              void* d_out, int out_size, void* d_ws, size_t ws_size,
                              hipStream_t stream) {
  (void)in_sizes; (void)n_in; (void)out_size; (void)ws_size;
  const float* nf   = (const float*)d_in[0];
  const int*   ei   = (const int*)d_in[1];
  const float* sw1  = (const float*)d_in[2];
  const float* sb1  = (const float*)d_in[3];
  const float* sw2  = (const float*)d_in[4];
  const float* sb2  = (const float*)d_in[5];
  const float* wih0 = (const float*)d_in[6];
  const float* whh0 = (const float*)d_in[7];
  const float* bih0 = (const float*)d_in[8];
  const float* bhh0 = (const float*)d_in[9];
  const float* wih1 = (const float*)d_in[10];
  const float* whh1 = (const float*)d_in[11];
  const float* bih1 = (const float*)d_in[12];
  const float* bhh1 = (const float*)d_in[13];
  const float* aw   = (const float*)d_in[14];
  const float* ab   = (const float*)d_in[15];
  const float* ow   = (const float*)d_in[16];
  const float* ob   = (const float*)d_in[17];
  const float* pw1  = (const float*)d_in[18];
  const float* pb1  = (const float*)d_in[19];
  const float* pw2  = (const float*)d_in[20];
  const float* pb2  = (const float*)d_in[21];
  const float* pw3  = (const float*)d_in[22];
  const float* pb3  = (const float*)d_in[23];

  char* ws = (char*)d_ws;
  float* wT = (float*)ws;                                   //   0   (~384 KB)
  int* cnt  = (int*)(ws + 524288);                          // 512 KB (256 KB)
  int* fill = (int*)(ws + 786432);                          // 768 KB (256 KB)
  int* rp   = (int*)(ws + 1048576);                         //   1 MB (~256 KB)
  int* col  = (int*)(ws + 1572864);                         // 1.5 MB (8 MB)
  unsigned short* henc = (unsigned short*)(ws + 10485760);  //  10 MB (32 MB)
  unsigned short* hmp  = (unsigned short*)(ws + 44040192);  //  42 MB (32 MB)
  unsigned short* x2   = henc;   // alias: henc dead after k_mp
  float* outp = (float*)d_out;

  hipMemsetAsync(ws + 524288, 0, 524288, stream);           // zero cnt+fill
  k_prep<<<64, 256, 0, stream>>>(wih0, whh0, bih0, bhh0, wih1, whh1, bih1, bhh1, wT);
  k_prep2<<<32, 256, 0, stream>>>(aw, ab, ow, pw1, pw2, pw3, wT);
  k_enc<<<1024, 256, 0, stream>>>(nf, sw1, sb1, sw2, sb2, henc);
  k_count<<<8192, 256, 0, stream>>>(ei, cnt);
  k_scan<<<16, 256, 0, stream>>>(cnt, rp);
  k_scatter<<<8192, 256, 0, stream>>>(ei, rp, fill, col);
  k_mp<<<16384, 256, 0, stream>>>(henc, rp, col, hmp);
  k_lstm<<<256, 1024, 0, stream>>>(hmp, wT, x2);
  k_attn<<<4096, 256, 0, stream>>>(x2, wT, aw, ob, pb1, pb2, pb3, outp);
}

// Round 3
// 654.821 us; speedup vs baseline: 2.6676x; 1.5324x over previous
//
#include <hip/hip_runtime.h>

#define Bq 4
#define Tq 16
#define Nq 4096
#define NFq 8
#define Hq 64
#define Eq 131072
#define Cq 13
#define Mq (Bq*Nq)

typedef __attribute__((ext_vector_type(8))) short bf16x8;
typedef __attribute__((ext_vector_type(4))) float f32x4;

// ---------- helpers ----------
__device__ __forceinline__ float bf2f(unsigned short u) {
  return __uint_as_float(((unsigned int)u) << 16);
}
__device__ __forceinline__ unsigned short f2bf(float f) {
  unsigned int x = __float_as_uint(f);
  unsigned int r = x + 0x7fff + ((x >> 16) & 1);
  return (unsigned short)(r >> 16);
}
__device__ __forceinline__ float sigf(float x) { return 1.f / (1.f + __expf(-x)); }
__device__ __forceinline__ float tanh_f(float x) {
  float xc = fminf(fmaxf(x, -15.f), 15.f);
  float e = __expf(2.f * xc);
  return (e - 1.f) / (e + 1.f);
}

// wT float offsets
#define O_WIH0 0
#define O_WHH0 16384
#define O_WIH1 32768
#define O_WHH1 49152
#define O_BC0  65536
#define O_BC1  65792
#define O_AQT  66048
#define O_QB   70144
#define O_WVT  70208
#define O_VB   74304
#define O_OWT  74368
#define O_P1T  78464
#define O_P2T  86656
#define O_P3T  94848

// ---------- K0: LSTM weight transpose + bias combine ----------
__global__ __launch_bounds__(256) void k_prep(
    const float* __restrict__ wih0, const float* __restrict__ whh0,
    const float* __restrict__ bih0, const float* __restrict__ bhh0,
    const float* __restrict__ wih1, const float* __restrict__ whh1,
    const float* __restrict__ bih1, const float* __restrict__ bhh1,
    float* __restrict__ wT) {
  int i = blockIdx.x * 256 + threadIdx.x;   // 0..16383
  int r = i >> 6, k = i & 63;
  int td = k * 256 + r;                      // transposed [k][row]
  wT[O_WIH0 + td] = wih0[i];
  wT[O_WHH0 + td] = whh0[i];
  wT[O_WIH1 + td] = wih1[i];
  wT[O_WHH1 + td] = whh1[i];
  if (i < 256) {
    wT[O_BC0 + i] = bih0[i] + bhh0[i];
    wT[O_BC1 + i] = bih1[i] + bhh1[i];
  }
}

// ---------- K0a: pack LSTM weights into MFMA A-fragments (bf16) ----------
// WA[L][mt(16)][ks(4)][lane(64)][j(8)]: A row (gate) = 16mt + (lane&15),
// k = 32ks + 8*(lane>>4) + j;  k<64 -> wih, k>=64 -> whh
__global__ __launch_bounds__(256) void k_prep_wa(
    const float* __restrict__ wih0, const float* __restrict__ whh0,
    const float* __restrict__ wih1, const float* __restrict__ whh1,
    unsigned short* __restrict__ WA) {
  int i = blockIdx.x * 256 + threadIdx.x;    // 0..65535
  int j = i & 7, lane = (i >> 3) & 63, ks = (i >> 9) & 3;
  int mt = (i >> 11) & 15, L = (i >> 15) & 1;
  int gate = 16 * mt + (lane & 15);
  int k = 32 * ks + 8 * (lane >> 4) + j;
  const float* w = L ? (k < 64 ? wih1 : whh1) : (k < 64 ? wih0 : whh0);
  WA[i] = f2bf(w[gate * 64 + (k & 63)]);
}

// ---------- K0b: attention/MLP weight transposes ----------
__global__ __launch_bounds__(256) void k_prep2(
    const float* __restrict__ aw, const float* __restrict__ ab,
    const float* __restrict__ ow,
    const float* __restrict__ pw1, const float* __restrict__ pw2,
    const float* __restrict__ pw3, float* __restrict__ wT) {
  int i = blockIdx.x * 256 + threadIdx.x;   // 0..8191
  if (i < 4096) {
    int k = i >> 6, ch = i & 63;
    wT[O_AQT + i] = 0.25f * aw[ch * 64 + k];
    wT[O_WVT + i] = aw[(128 + ch) * 64 + k];
    wT[O_OWT + i] = ow[ch * 64 + k];
  }
  if (i < 64) {
    wT[O_QB + i] = 0.25f * ab[i];
    wT[O_VB + i] = ab[128 + i];
  }
  {
    int k = i >> 7, ch = i & 127;
    wT[O_P1T + i] = pw1[ch * 64 + k];
  }
  {
    int k = i >> 6, ch = i & 63;
    wT[O_P2T + i] = pw2[ch * 128 + k];
  }
  if (i < 1024) {
    int k = i >> 4, c = i & 15;
    wT[O_P3T + i] = (c < 13) ? pw3[c * 64 + k] : 0.f;
  }
}

// ---------- K1: spatial encoder ----------
__global__ __launch_bounds__(256) void k_enc(
    const float* __restrict__ nf, const float* __restrict__ w1,
    const float* __restrict__ b1, const float* __restrict__ w2,
    const float* __restrict__ b2, unsigned short* __restrict__ henc) {
  int row = blockIdx.x * 256 + threadIdx.x;
  const float4* nf4 = (const float4*)(nf + (size_t)row * NFq);
  float4 aa = nf4[0], bb4 = nf4[1];
  float x0 = aa.x, x1 = aa.y, x2v = aa.z, x3 = aa.w;
  float x4 = bb4.x, x5 = bb4.y, x6 = bb4.z, x7 = bb4.w;
  float h1[Hq];
  #pragma unroll 8
  for (int j = 0; j < Hq; ++j) {
    const float* wr = w1 + j * NFq;
    float acc = b1[j] + wr[0]*x0 + wr[1]*x1 + wr[2]*x2v + wr[3]*x3
                      + wr[4]*x4 + wr[5]*x5 + wr[6]*x6 + wr[7]*x7;
    h1[j] = fmaxf(acc, 0.f);
  }
  uint4* dst = (uint4*)(henc + (size_t)row * Hq);
  #pragma unroll 1
  for (int q4 = 0; q4 < 8; ++q4) {
    unsigned int pk[4];
    #pragma unroll
    for (int pp = 0; pp < 4; ++pp) {
      int j0 = q4 * 8 + pp * 2;
      float a0 = b2[j0], a1 = b2[j0 + 1];
      const float* wr0 = w2 + j0 * Hq;
      const float* wr1 = wr0 + Hq;
      #pragma unroll
      for (int k = 0; k < Hq; ++k) { a0 += wr0[k] * h1[k]; a1 += wr1[k] * h1[k]; }
      pk[pp] = (unsigned int)f2bf(a0) | ((unsigned int)f2bf(a1) << 16);
    }
    uint4 v; v.x = pk[0]; v.y = pk[1]; v.z = pk[2]; v.w = pk[3];
    dst[q4] = v;
  }
}

// ---------- K2..K4: CSR build ----------
__global__ __launch_bounds__(256) void k_count(const int* __restrict__ ei,
                                               int* __restrict__ cnt) {
  int i = blockIdx.x * 256 + threadIdx.x;
  int t = i >> 17, e = i & (Eq - 1);
  int dst = ei[((t << 1) + 1) * Eq + e];
  atomicAdd(&cnt[(t << 12) + dst], 1);
}

__global__ __launch_bounds__(256) void k_scan(const int* __restrict__ cnt,
                                              int* __restrict__ rp) {
  int t = blockIdx.x, tid = threadIdx.x;
  __shared__ int part[256];
  int loc[16];
  int s = 0;
  #pragma unroll
  for (int j = 0; j < 16; ++j) { loc[j] = cnt[(t << 12) + tid * 16 + j]; s += loc[j]; }
  part[tid] = s;
  __syncthreads();
  if (tid == 0) {
    int run = 0;
    for (int i2 = 0; i2 < 256; ++i2) { int v = part[i2]; part[i2] = run; run += v; }
  }
  __syncthreads();
  int off = part[tid];
  #pragma unroll
  for (int j = 0; j < 16; ++j) { rp[t * (Nq + 1) + tid * 16 + j] = off; off += loc[j]; }
  if (tid == 255) rp[t * (Nq + 1) + Nq] = off;
}

__global__ __launch_bounds__(256) void k_scatter(const int* __restrict__ ei,
    const int* __restrict__ rp, int* __restrict__ fill, int* __restrict__ col) {
  int i = blockIdx.x * 256 + threadIdx.x;
  int t = i >> 17, e = i & (Eq - 1);
  int src = ei[(t << 1) * Eq + e];
  int dst = ei[((t << 1) + 1) * Eq + e];
  int pos = rp[t * (Nq + 1) + dst] + atomicAdd(&fill[(t << 12) + dst], 1);
  col[(t << 17) + pos] = src;
}

// ---------- K5: message passing ----------
__global__ __launch_bounds__(256) void k_mp(const unsigned short* __restrict__ henc,
    const int* __restrict__ rp, const int* __restrict__ col,
    unsigned short* __restrict__ hmp) {
  int lane = threadIdx.x & 63;
  int task = blockIdx.x * 4 + __builtin_amdgcn_readfirstlane(threadIdx.x >> 6);
  int t = task >> 12, n = task & 4095;
  const int* rpt = rp + t * (Nq + 1);
  const int* colt = col + (t << 17);
  int e0 = rpt[n], e1 = rpt[n + 1];
  const unsigned short* ht = henc + t * 262144;
  size_t loff = (size_t)(lane >> 4) * 4194304 + ((lane & 15) << 2);
  float a0 = 0.f, a1 = 0.f, a2 = 0.f, a3 = 0.f;
  for (int e = e0; e < e1; ++e) {
    int src = colt[e];
    uint2 p = *(const uint2*)(ht + loff + src * 64);
    a0 += bf2f((unsigned short)(p.x & 0xffff));
    a1 += bf2f((unsigned short)(p.x >> 16));
    a2 += bf2f((unsigned short)(p.y & 0xffff));
    a3 += bf2f((unsigned short)(p.y >> 16));
  }
  uint2 ps = *(const uint2*)(ht + loff + n * 64);
  unsigned short* po = hmp + t * 262144 + loff + n * 64;
  int deg = e1 - e0;
  uint2 out;
  if (deg > 0) {
    float sc = 0.5f / (float)deg;
    float s0 = bf2f((unsigned short)(ps.x & 0xffff)) * 0.5f + a0 * sc;
    float s1 = bf2f((unsigned short)(ps.x >> 16))    * 0.5f + a1 * sc;
    float s2 = bf2f((unsigned short)(ps.y & 0xffff)) * 0.5f + a2 * sc;
    float s3 = bf2f((unsigned short)(ps.y >> 16))    * 0.5f + a3 * sc;
    out.x = (unsigned int)f2bf(s0) | ((unsigned int)f2bf(s1) << 16);
    out.y = (unsigned int)f2bf(s2) | ((unsigned int)f2bf(s3) << 16);
  } else {
    out = ps;
  }
  *(uint2*)po = out;
}

// ---------- K6: fused 2-layer LSTM via MFMA ----------
// block = 1024 thr (16 waves) = 64 sequences; wave w: mtp=w>>1 (2 mtiles), ntp=w&1 (2 ntiles)
// G^T = Wc @ [X,H]^T : A = weights (VGPR-resident frags), B = X/H (LDS frag-packed)
__global__ __launch_bounds__(1024) void k_lstm(
    const unsigned short* __restrict__ hmp,
    const unsigned short* __restrict__ WA,
    const float* __restrict__ wT,
    unsigned short* __restrict__ x2) {
  __shared__ unsigned short XF[4096];    // [ks2][nt4][lane64][8]
  __shared__ unsigned short H0F[4096];
  __shared__ unsigned short H1F[4096];
  __shared__ unsigned short G[64 * 260]; // [seq][gate] stride 260
  __shared__ float BIAS[512];
  int tid = threadIdx.x;
  int l = tid & 63;
  int w = tid >> 6;
  int mtp = w >> 1, ntp = w & 1;
  int m0 = blockIdx.x << 6;

  // A-fragments (weights) -> VGPR, once
  bf16x8 afr[2][2][4];
  const bf16x8* wa8 = (const bf16x8*)WA;
  #pragma unroll
  for (int L = 0; L < 2; ++L)
    #pragma unroll
    for (int mt2 = 0; mt2 < 2; ++mt2)
      #pragma unroll
      for (int ks = 0; ks < 4; ++ks)
        afr[L][mt2][ks] = wa8[((L * 16 + (2 * mtp + mt2)) * 4 + ks) * 64 + l];

  for (int i = tid; i < 512; i += 1024) BIAS[i] = wT[O_BC0 + i];
  for (int i = tid; i < 4096; i += 1024) { H0F[i] = 0; H1F[i] = 0; }

  // activation/staging thread mapping: seq sA, channels [c4, c4+4)
  int sA = tid >> 4;
  int c4 = (tid & 15) << 2;
  int fl = (sA & 15) | (((c4 >> 3) & 3) << 4);
  int fragoff = (((c4 >> 5) * 4 + (sA >> 4)) * 64 + fl) * 8 + (c4 & 7);
  float c0[4] = {0.f, 0.f, 0.f, 0.f}, c1[4] = {0.f, 0.f, 0.f, 0.f};
  int mm = m0 + sA;
  int bb = mm >> 12, nn = mm & 4095;
  const unsigned short* src = hmp + ((size_t)(bb * 16) * 4096 + (size_t)nn) * 64 + c4;
  unsigned short* dst = x2 + (size_t)mm * (Tq * Hq) + c4;

  uint2 xv = *(const uint2*)(src);
  __syncthreads();

  for (int t = 0; t < Tq; ++t) {
    *(uint2*)(XF + fragoff) = xv;
    __syncthreads();
    if (t < Tq - 1) xv = *(const uint2*)(src + (t + 1) * 262144);

    // ---- layer 0 MFMA: B from XF (k<64) + H0F (k>=64)
    {
      f32x4 acc[2][2];
      #pragma unroll
      for (int a = 0; a < 2; ++a)
        #pragma unroll
        for (int b2 = 0; b2 < 2; ++b2) acc[a][b2] = (f32x4){0.f, 0.f, 0.f, 0.f};
      #pragma unroll
      for (int nt2 = 0; nt2 < 2; ++nt2) {
        int nt = 2 * ntp + nt2;
        #pragma unroll
        for (int ks = 0; ks < 4; ++ks) {
          const unsigned short* bsrc = (ks < 2) ? XF : H0F;
          bf16x8 bf = *(const bf16x8*)(bsrc + (((ks & 1) * 4 + nt) * 64 + l) * 8);
          acc[0][nt2] = __builtin_amdgcn_mfma_f32_16x16x32_bf16(afr[0][0][ks], bf, acc[0][nt2], 0, 0, 0);
          acc[1][nt2] = __builtin_amdgcn_mfma_f32_16x16x32_bf16(afr[0][1][ks], bf, acc[1][nt2], 0, 0, 0);
        }
      }
      #pragma unroll
      for (int mt2 = 0; mt2 < 2; ++mt2)
        #pragma unroll
        for (int nt2 = 0; nt2 < 2; ++nt2) {
          int seq = 16 * (2 * ntp + nt2) + (l & 15);
          int gat = 16 * (2 * mtp + mt2) + 4 * (l >> 4);
          uint2 gp;
          gp.x = (unsigned int)f2bf(acc[mt2][nt2][0]) | ((unsigned int)f2bf(acc[mt2][nt2][1]) << 16);
          gp.y = (unsigned int)f2bf(acc[mt2][nt2][2]) | ((unsigned int)f2bf(acc[mt2][nt2][3]) << 16);
          *(uint2*)(G + seq * 260 + gat) = gp;
        }
    }
    __syncthreads();
    // ---- activation 0 -> H0F
    {
      unsigned short hh[4];
      float gv[4][4];
      #pragma unroll
      for (int g = 0; g < 4; ++g) {
        uint2 p = *(const uint2*)(G + sA * 260 + g * 64 + c4);
        gv[g][0] = bf2f((unsigned short)(p.x & 0xffff)) + BIAS[g * 64 + c4];
        gv[g][1] = bf2f((unsigned short)(p.x >> 16))    + BIAS[g * 64 + c4 + 1];
        gv[g][2] = bf2f((unsigned short)(p.y & 0xffff)) + BIAS[g * 64 + c4 + 2];
        gv[g][3] = bf2f((unsigned short)(p.y >> 16))    + BIAS[g * 64 + c4 + 3];
      }
      #pragma unroll
      for (int i = 0; i < 4; ++i) {
        float ig = sigf(gv[0][i]);
        float fg = sigf(gv[1][i]);
        float gg = tanh_f(gv[2][i]);
        float og = sigf(gv[3][i]);
        float c = fg * c0[i] + ig * gg;
        c0[i] = c;
        hh[i] = f2bf(og * tanh_f(c));
      }
      uint2 hp;
      hp.x = (unsigned int)hh[0] | ((unsigned int)hh[1] << 16);
      hp.y = (unsigned int)hh[2] | ((unsigned int)hh[3] << 16);
      *(uint2*)(H0F + fragoff) = hp;
    }
    __syncthreads();
    // ---- layer 1 MFMA: B from H0F (k<64) + H1F (k>=64)
    {
      f32x4 acc[2][2];
      #pragma unroll
      for (int a = 0; a < 2; ++a)
        #pragma unroll
        for (int b2 = 0; b2 < 2; ++b2) acc[a][b2] = (f32x4){0.f, 0.f, 0.f, 0.f};
      #pragma unroll
      for (int nt2 = 0; nt2 < 2; ++nt2) {
        int nt = 2 * ntp + nt2;
        #pragma unroll
        for (int ks = 0; ks < 4; ++ks) {
          const unsigned short* bsrc = (ks < 2) ? H0F : H1F;
          bf16x8 bf = *(const bf16x8*)(bsrc + (((ks & 1) * 4 + nt) * 64 + l) * 8);
          acc[0][nt2] = __builtin_amdgcn_mfma_f32_16x16x32_bf16(afr[1][0][ks], bf, acc[0][nt2], 0, 0, 0);
          acc[1][nt2] = __builtin_amdgcn_mfma_f32_16x16x32_bf16(afr[1][1][ks], bf, acc[1][nt2], 0, 0, 0);
        }
      }
      #pragma unroll
      for (int mt2 = 0; mt2 < 2; ++mt2)
        #pragma unroll
        for (int nt2 = 0; nt2 < 2; ++nt2) {
          int seq = 16 * (2 * ntp + nt2) + (l & 15);
          int gat = 16 * (2 * mtp + mt2) + 4 * (l >> 4);
          uint2 gp;
          gp.x = (unsigned int)f2bf(acc[mt2][nt2][0]) | ((unsigned int)f2bf(acc[mt2][nt2][1]) << 16);
          gp.y = (unsigned int)f2bf(acc[mt2][nt2][2]) | ((unsigned int)f2bf(acc[mt2][nt2][3]) << 16);
          *(uint2*)(G + seq * 260 + gat) = gp;
        }
    }
    __syncthreads();
    // ---- activation 1 -> H1F + global x2
    {
      unsigned short hh[4];
      float gv[4][4];
      #pragma unroll
      for (int g = 0; g < 4; ++g) {
        uint2 p = *(const uint2*)(G + sA * 260 + g * 64 + c4);
        gv[g][0] = bf2f((unsigned short)(p.x & 0xffff)) + BIAS[256 + g * 64 + c4];
        gv[g][1] = bf2f((unsigned short)(p.x >> 16))    + BIAS[256 + g * 64 + c4 + 1];
        gv[g][2] = bf2f((unsigned short)(p.y & 0xffff)) + BIAS[256 + g * 64 + c4 + 2];
        gv[g][3] = bf2f((unsigned short)(p.y >> 16))    + BIAS[256 + g * 64 + c4 + 3];
      }
      #pragma unroll
      for (int i = 0; i < 4; ++i) {
        float ig = sigf(gv[0][i]);
        float fg = sigf(gv[1][i]);
        float gg = tanh_f(gv[2][i]);
        float og = sigf(gv[3][i]);
        float c = fg * c1[i] + ig * gg;
        c1[i] = c;
        hh[i] = f2bf(og * tanh_f(c));
      }
      uint2 hp;
      hp.x = (unsigned int)hh[0] | ((unsigned int)hh[1] << 16);
      hp.y = (unsigned int)hh[2] | ((unsigned int)hh[3] << 16);
      *(uint2*)(H1F + fragoff) = hp;
      *(uint2*)(dst + t * 64) = hp;
    }
    __syncthreads();
  }
}

// ---------- K7: attention (folded) + MLP ----------
__global__ __launch_bounds__(256) void k_attn(const unsigned short* __restrict__ x2,
    const float* __restrict__ wp, const float* __restrict__ aw,
    const float* __restrict__ obv, const float* __restrict__ pb1,
    const float* __restrict__ pb2, const float* __restrict__ pb3,
    float* __restrict__ outp) {
  __shared__ float smem[8192];
  int lane = threadIdx.x & 63;
  float* W = smem + ((threadIdx.x >> 6) << 11);
  int m = (blockIdx.x << 2) + (threadIdx.x >> 6);
  const uint4* xp = (const uint4*)(x2 + (size_t)m * 1024);
  #pragma unroll
  for (int u = 0; u < 2; ++u) {
    uint4 pv = xp[lane * 2 + u];
    int f0 = (lane * 2 + u) * 8;
    unsigned int ww[4] = {pv.x, pv.y, pv.z, pv.w};
    #pragma unroll
    for (int j = 0; j < 4; ++j) {
      int f = f0 + j * 2;
      int t = f >> 6, ch = f & 63;
      W[t * 65 + ch]     = bf2f((unsigned short)(ww[j] & 0xffff));
      W[t * 65 + ch + 1] = bf2f((unsigned short)(ww[j] >> 16));
    }
  }
  __syncthreads();
  {
    float qacc = wp[O_QB + lane];
    const float* aqT = wp + O_AQT;
    #pragma unroll 4
    for (int kk = 0; kk < 64; ++kk) qacc += aqT[kk * 64 + lane] * W[15 * 65 + kk];
    W[1040 + lane] = qacc;
  }
  __syncthreads();
  #pragma unroll
  for (int h = 0; h < 4; ++h) {
    float a = 0.f;
    #pragma unroll 4
    for (int d = 0; d < 16; ++d) {
      float coef = W[1040 + h * 16 + d];
      a += aw[(64 + h * 16 + d) * 64 + lane] * coef;
    }
    W[1104 + h * 68 + lane] = a;
  }
  __syncthreads();
  {
    int hh = lane >> 4, tt2 = lane & 15;
    float sc = 0.f;
    #pragma unroll 4
    for (int ch = 0; ch < 64; ++ch)
      sc += W[1104 + hh * 68 + ch] * W[tt2 * 65 + ch];
    float mx = sc;
    mx = fmaxf(mx, __shfl_xor(mx, 1));
    mx = fmaxf(mx, __shfl_xor(mx, 2));
    mx = fmaxf(mx, __shfl_xor(mx, 4));
    mx = fmaxf(mx, __shfl_xor(mx, 8));
    float e = __expf(sc - mx);
    float sum = e;
    sum += __shfl_xor(sum, 1);
    sum += __shfl_xor(sum, 2);
    sum += __shfl_xor(sum, 4);
    sum += __shfl_xor(sum, 8);
    W[1376 + lane] = e / sum;
  }
  __syncthreads();
  {
    float hb[4] = {0.f, 0.f, 0.f, 0.f};
    for (int t = 0; t < 16; ++t) {
      float xv = W[t * 65 + lane];
      #pragma unroll
      for (int h = 0; h < 4; ++h) hb[h] += W[1376 + h * 16 + t] * xv;
    }
    #pragma unroll
    for (int h = 0; h < 4; ++h) W[1440 + h * 68 + lane] = hb[h];
  }
  __syncthreads();
  {
    const float* wvT = wp + O_WVT;
    float oacc = wp[O_VB + lane];
    int hsel = lane >> 4;
    #pragma unroll 4
    for (int k = 0; k < 64; ++k) oacc += wvT[k * 64 + lane] * W[1440 + hsel * 68 + k];
    W[1712 + lane] = oacc;
  }
  __syncthreads();
  {
    const float* owT = wp + O_OWT;
    float facc = obv[lane];
    #pragma unroll 4
    for (int k = 0; k < 64; ++k) facc += owT[k * 64 + lane] * W[1712 + k];
    W[1776 + lane] = facc;
  }
  __syncthreads();
  {
    const float* p1T = wp + O_P1T;
    float a0 = pb1[lane], a1 = pb1[64 + lane];
    #pragma unroll 4
    for (int k = 0; k < 64; ++k) {
      float fv = W[1776 + k];
      a0 += p1T[k * 128 + lane] * fv;
      a1 += p1T[k * 128 + 64 + lane] * fv;
    }
    W[1840 + lane] = fmaxf(a0, 0.f);
    W[1904 + lane] = fmaxf(a1, 0.f);
  }
  __syncthreads();
  {
    const float* p2T = wp + O_P2T;
    float a2 = pb2[lane];
    #pragma unroll 4
    for (int k = 0; k < 128; ++k) a2 += p2T[k * 64 + lane] * W[1840 + k];
    W[1968 + lane] = fmaxf(a2, 0.f);
  }
  __syncthreads();
  if (lane < 13) {
    const float* p3T = wp + O_P3T;
    float a3 = pb3[lane];
    #pragma unroll 4
    for (int k = 0; k < 64; ++k) a3 += p3T[k * 16 + lane] * W[1968 + k];
    outp[(size_t)m * 13 + lane] = a3;
  }
}

extern "C" void kernel_launch(void* const* d_in, const int* in_sizes, int n_in,
                              void* d_out, int out_size, void* d_ws, size_t ws_size,
                              hipStream_t stream) {
  (void)in_sizes; (void)n_in; (void)out_size; (void)ws_size;
  const float* nf   = (const float*)d_in[0];
  const int*   ei   = (const int*)d_in[1];
  const float* sw1  = (const float*)d_in[2];
  const float* sb1  = (const float*)d_in[3];
  const float* sw2  = (const float*)d_in[4];
  const float* sb2  = (const float*)d_in[5];
  const float* wih0 = (const float*)d_in[6];
  const float* whh0 = (const float*)d_in[7];
  const float* bih0 = (const float*)d_in[8];
  const float* bhh0 = (const float*)d_in[9];
  const float* wih1 = (const float*)d_in[10];
  const float* whh1 = (const float*)d_in[11];
  const float* bih1 = (const float*)d_in[12];
  const float* bhh1 = (const float*)d_in[13];
  const float* aw   = (const float*)d_in[14];
  const float* ab   = (const float*)d_in[15];
  const float* ow   = (const float*)d_in[16];
  const float* ob   = (const float*)d_in[17];
  const float* pw1  = (const float*)d_in[18];
  const float* pb1  = (const float*)d_in[19];
  const float* pw2  = (const float*)d_in[20];
  const float* pb2  = (const float*)d_in[21];
  const float* pw3  = (const float*)d_in[22];
  const float* pb3  = (const float*)d_in[23];

  char* ws = (char*)d_ws;
  float* wT = (float*)ws;                                   //   0 .. 384 KB
  unsigned short* WA = (unsigned short*)(ws + 393216);      // 384 KB (128 KB)
  int* cnt  = (int*)(ws + 524288);                          // 512 KB (256 KB)
  int* fill = (int*)(ws + 786432);                          // 768 KB (256 KB)
  int* rp   = (int*)(ws + 1048576);                         //   1 MB (~256 KB)
  int* col  = (int*)(ws + 1572864);                         // 1.5 MB (8 MB)
  unsigned short* henc = (unsigned short*)(ws + 10485760);  //  10 MB (32 MB)
  unsigned short* hmp  = (unsigned short*)(ws + 44040192);  //  42 MB (32 MB)
  unsigned short* x2   = henc;   // alias: henc dead after k_mp
  float* outp = (float*)d_out;

  hipMemsetAsync(ws + 524288, 0, 524288, stream);
  k_prep<<<64, 256, 0, stream>>>(wih0, whh0, bih0, bhh0, wih1, whh1, bih1, bhh1, wT);
  k_prep_wa<<<256, 256, 0, stream>>>(wih0, whh0, wih1, whh1, WA);
  k_prep2<<<32, 256, 0, stream>>>(aw, ab, ow, pw1, pw2, pw3, wT);
  k_enc<<<1024, 256, 0, stream>>>(nf, sw1, sb1, sw2, sb2, henc);
  k_count<<<8192, 256, 0, stream>>>(ei, cnt);
  k_scan<<<16, 256, 0, stream>>>(cnt, rp);
  k_scatter<<<8192, 256, 0, stream>>>(ei, rp, fill, col);
  k_mp<<<16384, 256, 0, stream>>>(henc, rp, col, hmp);
  k_lstm<<<256, 1024, 0, stream>>>(hmp, WA, wT, x2);
  k_attn<<<4096, 256, 0, stream>>>(x2, wT, aw, ob, pb1, pb2, pb3, outp);
}

// Round 4
// 609.020 us; speedup vs baseline: 2.8682x; 1.0752x over previous
//
#include <hip/hip_runtime.h>

#define Bq 4
#define Tq 16
#define Nq 4096
#define NFq 8
#define Hq 64
#define Eq 131072
#define Cq 13
#define Mq (Bq*Nq)

typedef __attribute__((ext_vector_type(8))) short bf16x8;
typedef __attribute__((ext_vector_type(4))) float f32x4;

// ---------- helpers ----------
__device__ __forceinline__ float bf2f(unsigned short u) {
  return __uint_as_float(((unsigned int)u) << 16);
}
__device__ __forceinline__ unsigned short f2bf(float f) {
  unsigned int x = __float_as_uint(f);
  unsigned int r = x + 0x7fff + ((x >> 16) & 1);
  return (unsigned short)(r >> 16);
}
__device__ __forceinline__ float sigf(float x) { return 1.f / (1.f + __expf(-x)); }
__device__ __forceinline__ float tanh_f(float x) {
  float xc = fminf(fmaxf(x, -15.f), 15.f);
  float e = __expf(2.f * xc);
  return (e - 1.f) / (e + 1.f);
}

// wT float offsets
#define O_WIH0 0
#define O_WHH0 16384
#define O_WIH1 32768
#define O_WHH1 49152
#define O_BC0  65536
#define O_BC1  65792
#define O_AQT  66048
#define O_QB   70144
#define O_WVT  70208
#define O_VB   74304
#define O_OWT  74368
#define O_P1T  78464
#define O_P2T  86656
#define O_P3T  94848

// ---------- K0: LSTM bias combine (+ legacy transposes kept for layout) ----------
__global__ __launch_bounds__(256) void k_prep(
    const float* __restrict__ wih0, const float* __restrict__ whh0,
    const float* __restrict__ bih0, const float* __restrict__ bhh0,
    const float* __restrict__ wih1, const float* __restrict__ whh1,
    const float* __restrict__ bih1, const float* __restrict__ bhh1,
    float* __restrict__ wT) {
  int i = blockIdx.x * 256 + threadIdx.x;   // 0..16383
  (void)wih0; (void)whh0; (void)wih1; (void)whh1;
  if (i < 256) {
    wT[O_BC0 + i] = bih0[i] + bhh0[i];
    wT[O_BC1 + i] = bih1[i] + bhh1[i];
  }
}

// ---------- K0a: pack LSTM weights into MFMA A-fragments, GATE-INTERLEAVED ----------
// A-row r' = 4*ch + gate  (so C-frag acc[j] = gate j of one channel)
// WA[L][mt(16)][ks(4)][lane(64)][j(8)]: r' = 16mt + (lane&15),
// k = 32ks + 8*(lane>>4) + j;  k<64 -> wih[orig][k], else whh[orig][k-64]
__global__ __launch_bounds__(256) void k_prep_wa(
    const float* __restrict__ wih0, const float* __restrict__ whh0,
    const float* __restrict__ wih1, const float* __restrict__ whh1,
    unsigned short* __restrict__ WA) {
  int i = blockIdx.x * 256 + threadIdx.x;    // 0..65535
  int j = i & 7, lane = (i >> 3) & 63, ks = (i >> 9) & 3;
  int mt = (i >> 11) & 15, L = (i >> 15) & 1;
  int rp = 16 * mt + (lane & 15);
  int orig = (rp & 3) * 64 + (rp >> 2);      // gate-major original row
  int k = 32 * ks + 8 * (lane >> 4) + j;
  const float* w = L ? (k < 64 ? wih1 : whh1) : (k < 64 ? wih0 : whh0);
  WA[i] = f2bf(w[orig * 64 + (k & 63)]);
}

// ---------- K0b: attention/MLP weight transposes ----------
__global__ __launch_bounds__(256) void k_prep2(
    const float* __restrict__ aw, const float* __restrict__ ab,
    const float* __restrict__ ow,
    const float* __restrict__ pw1, const float* __restrict__ pw2,
    const float* __restrict__ pw3, float* __restrict__ wT) {
  int i = blockIdx.x * 256 + threadIdx.x;   // 0..8191
  if (i < 4096) {
    int k = i >> 6, ch = i & 63;
    wT[O_AQT + i] = 0.25f * aw[ch * 64 + k];
    wT[O_WVT + i] = aw[(128 + ch) * 64 + k];
    wT[O_OWT + i] = ow[ch * 64 + k];
  }
  if (i < 64) {
    wT[O_QB + i] = 0.25f * ab[i];
    wT[O_VB + i] = ab[128 + i];
  }
  {
    int k = i >> 7, ch = i & 127;
    wT[O_P1T + i] = pw1[ch * 64 + k];
  }
  {
    int k = i >> 6, ch = i & 63;
    wT[O_P2T + i] = pw2[ch * 128 + k];
  }
  if (i < 1024) {
    int k = i >> 4, c = i & 15;
    wT[O_P3T + i] = (c < 13) ? pw3[c * 64 + k] : 0.f;
  }
}

// ---------- K1: spatial encoder (spill-free: high VGPR budget) ----------
__global__ __launch_bounds__(256, 2) void k_enc(
    const float* __restrict__ nf, const float* __restrict__ w1,
    const float* __restrict__ b1, const float* __restrict__ w2,
    const float* __restrict__ b2, unsigned short* __restrict__ henc) {
  int row = blockIdx.x * 256 + threadIdx.x;
  const float4* nf4 = (const float4*)(nf + (size_t)row * NFq);
  float4 aa = nf4[0], bb4 = nf4[1];
  float x0 = aa.x, x1 = aa.y, x2v = aa.z, x3 = aa.w;
  float x4 = bb4.x, x5 = bb4.y, x6 = bb4.z, x7 = bb4.w;
  float h1[Hq];
  #pragma unroll
  for (int j = 0; j < Hq; ++j) {
    const float* wr = w1 + j * NFq;
    float acc = b1[j] + wr[0]*x0 + wr[1]*x1 + wr[2]*x2v + wr[3]*x3
                      + wr[4]*x4 + wr[5]*x5 + wr[6]*x6 + wr[7]*x7;
    h1[j] = fmaxf(acc, 0.f);
  }
  uint4* dst = (uint4*)(henc + (size_t)row * Hq);
  #pragma unroll 1
  for (int q4 = 0; q4 < 8; ++q4) {
    unsigned int pk[4];
    #pragma unroll
    for (int pp = 0; pp < 4; ++pp) {
      int j0 = q4 * 8 + pp * 2;
      float a0 = b2[j0], a1 = b2[j0 + 1];
      const float* wr0 = w2 + j0 * Hq;
      const float* wr1 = wr0 + Hq;
      #pragma unroll
      for (int k = 0; k < Hq; ++k) { a0 += wr0[k] * h1[k]; a1 += wr1[k] * h1[k]; }
      pk[pp] = (unsigned int)f2bf(a0) | ((unsigned int)f2bf(a1) << 16);
    }
    uint4 v; v.x = pk[0]; v.y = pk[1]; v.z = pk[2]; v.w = pk[3];
    dst[q4] = v;
  }
}

// ---------- K2..K4: CSR build ----------
__global__ __launch_bounds__(256) void k_count(const int* __restrict__ ei,
                                               int* __restrict__ cnt) {
  int i = blockIdx.x * 256 + threadIdx.x;
  int t = i >> 17, e = i & (Eq - 1);
  int dst = ei[((t << 1) + 1) * Eq + e];
  atomicAdd(&cnt[(t << 12) + dst], 1);
}

__global__ __launch_bounds__(256) void k_scan(const int* __restrict__ cnt,
                                              int* __restrict__ rp) {
  int t = blockIdx.x, tid = threadIdx.x;
  __shared__ int part[256];
  int loc[16];
  int s = 0;
  #pragma unroll
  for (int j = 0; j < 16; ++j) { loc[j] = cnt[(t << 12) + tid * 16 + j]; s += loc[j]; }
  part[tid] = s;
  __syncthreads();
  if (tid == 0) {
    int run = 0;
    for (int i2 = 0; i2 < 256; ++i2) { int v = part[i2]; part[i2] = run; run += v; }
  }
  __syncthreads();
  int off = part[tid];
  #pragma unroll
  for (int j = 0; j < 16; ++j) { rp[t * (Nq + 1) + tid * 16 + j] = off; off += loc[j]; }
  if (tid == 255) rp[t * (Nq + 1) + Nq] = off;
}

__global__ __launch_bounds__(256) void k_scatter(const int* __restrict__ ei,
    const int* __restrict__ rp, int* __restrict__ fill, int* __restrict__ col) {
  int i = blockIdx.x * 256 + threadIdx.x;
  int t = i >> 17, e = i & (Eq - 1);
  int src = ei[(t << 1) * Eq + e];
  int dst = ei[((t << 1) + 1) * Eq + e];
  int pos = rp[t * (Nq + 1) + dst] + atomicAdd(&fill[(t << 12) + dst], 1);
  col[(t << 17) + pos] = src;
}

// ---------- K5: message passing ----------
__global__ __launch_bounds__(256) void k_mp(const unsigned short* __restrict__ henc,
    const int* __restrict__ rp, const int* __restrict__ col,
    unsigned short* __restrict__ hmp) {
  int lane = threadIdx.x & 63;
  int task = blockIdx.x * 4 + __builtin_amdgcn_readfirstlane(threadIdx.x >> 6);
  int t = task >> 12, n = task & 4095;
  const int* rpt = rp + t * (Nq + 1);
  const int* colt = col + (t << 17);
  int e0 = rpt[n], e1 = rpt[n + 1];
  const unsigned short* ht = henc + t * 262144;
  size_t loff = (size_t)(lane >> 4) * 4194304 + ((lane & 15) << 2);
  float a0 = 0.f, a1 = 0.f, a2 = 0.f, a3 = 0.f;
  for (int e = e0; e < e1; ++e) {
    int src = colt[e];
    uint2 p = *(const uint2*)(ht + loff + src * 64);
    a0 += bf2f((unsigned short)(p.x & 0xffff));
    a1 += bf2f((unsigned short)(p.x >> 16));
    a2 += bf2f((unsigned short)(p.y & 0xffff));
    a3 += bf2f((unsigned short)(p.y >> 16));
  }
  uint2 ps = *(const uint2*)(ht + loff + n * 64);
  unsigned short* po = hmp + t * 262144 + loff + n * 64;
  int deg = e1 - e0;
  uint2 out;
  if (deg > 0) {
    float sc = 0.5f / (float)deg;
    float s0 = bf2f((unsigned short)(ps.x & 0xffff)) * 0.5f + a0 * sc;
    float s1 = bf2f((unsigned short)(ps.x >> 16))    * 0.5f + a1 * sc;
    float s2 = bf2f((unsigned short)(ps.y & 0xffff)) * 0.5f + a2 * sc;
    float s3 = bf2f((unsigned short)(ps.y >> 16))    * 0.5f + a3 * sc;
    out.x = (unsigned int)f2bf(s0) | ((unsigned int)f2bf(s1) << 16);
    out.y = (unsigned int)f2bf(s2) | ((unsigned int)f2bf(s3) << 16);
  } else {
    out = ps;
  }
  *(uint2*)po = out;
}

// ---------- K6: fused 2-layer LSTM, MFMA + in-register activation ----------
// block = 1024 thr (16 waves) = 64 seqs; wave: mtp=w>>1 (mtiles 2mtp,2mtp+1), ntp=w&1
// Gate-interleaved A rows: acc[mt2][nt2][j] = gate j of (ch=4mt+(l>>4), seq=16nt+(l&15))
__global__ __launch_bounds__(1024) void k_lstm(
    const unsigned short* __restrict__ hmp,
    const unsigned short* __restrict__ WA,
    const float* __restrict__ wT,
    unsigned short* __restrict__ x2) {
  __shared__ unsigned short XF[4096];       // [p2][nt4][l64][8]
  __shared__ unsigned short H0F[2][4096];   // double-buffered
  __shared__ unsigned short H1F[2][4096];
  __shared__ unsigned short OUTB[64 * 68];  // [seq][ch] stride 68
  int tid = threadIdx.x;
  int l = tid & 63;
  int w = tid >> 6;
  int mtp = w >> 1, ntp = w & 1;
  int m0 = blockIdx.x << 6;

  // A-fragments (both layers) -> VGPR, once
  bf16x8 afr[2][2][4];
  const bf16x8* wa8 = (const bf16x8*)WA;
  #pragma unroll
  for (int L = 0; L < 2; ++L)
    #pragma unroll
    for (int mt2 = 0; mt2 < 2; ++mt2)
      #pragma unroll
      for (int ks = 0; ks < 4; ++ks)
        afr[L][mt2][ks] = wa8[((L * 16 + (2 * mtp + mt2)) * 4 + ks) * 64 + l];

  // per-lane bias (gates 0..3 of ch), h-frag write bases, OUT bases
  float4 bias0[2], bias1[2];
  int hbase[2], obase[2];
  #pragma unroll
  for (int mt2 = 0; mt2 < 2; ++mt2) {
    int ch = 4 * (2 * mtp + mt2) + (l >> 4);
    bias0[mt2].x = wT[O_BC0 + ch];       bias0[mt2].y = wT[O_BC0 + 64 + ch];
    bias0[mt2].z = wT[O_BC0 + 128 + ch]; bias0[mt2].w = wT[O_BC0 + 192 + ch];
    bias1[mt2].x = wT[O_BC1 + ch];       bias1[mt2].y = wT[O_BC1 + 64 + ch];
    bias1[mt2].z = wT[O_BC1 + 128 + ch]; bias1[mt2].w = wT[O_BC1 + 192 + ch];
    int l2 = (l & 15) | (((ch >> 3) & 3) << 4);
    hbase[mt2] = (ch >> 5) * 2048 + l2 * 8 + (ch & 7);
    obase[mt2] = (l & 15) * 68 + ch;
  }
  float c0a[2][2] = {{0.f, 0.f}, {0.f, 0.f}};
  float c1a[2][2] = {{0.f, 0.f}, {0.f, 0.f}};

  // staging / copy thread mapping
  int sA = tid >> 4, c4 = (tid & 15) << 2;
  int xfidx = (((c4 >> 5) * 4 + (sA >> 4)) * 64 + ((sA & 15) | (((c4 >> 3) & 3) << 4))) * 8 + (c4 & 7);
  int mm = m0 + sA;
  int bb = mm >> 12, nn = mm & 4095;
  const unsigned short* srcb = hmp + ((size_t)(bb * 16) * 4096 + (size_t)nn) * 64 + c4;
  unsigned short* x2g = x2 + (size_t)mm * (Tq * Hq) + c4;
  int outsrc = sA * 68 + c4;

  // zero H buffers
  int* hz0 = (int*)&H0F[0][0];
  int* hz1 = (int*)&H1F[0][0];
  for (int i = tid; i < 4096; i += 1024) { hz0[i] = 0; hz1[i] = 0; }

  uint2 xv = *(const uint2*)srcb;
  __syncthreads();

  for (int t = 0; t < Tq; ++t) {
    int cur = t & 1, prv = cur ^ 1;
    *(uint2*)(XF + xfidx) = xv;
    __syncthreads();
    if (t < Tq - 1) xv = *(const uint2*)(srcb + (t + 1) * 262144);

    // ---- layer 0: MFMA (reads XF, H0F[prv])
    {
      f32x4 acc[2][2];
      #pragma unroll
      for (int mt2 = 0; mt2 < 2; ++mt2)
        #pragma unroll
        for (int nt2 = 0; nt2 < 2; ++nt2) {
          float4 bv = bias0[mt2];
          acc[mt2][nt2] = (f32x4){bv.x, bv.y, bv.z, bv.w};
        }
      #pragma unroll
      for (int nt2 = 0; nt2 < 2; ++nt2) {
        int nt = 2 * ntp + nt2;
        #pragma unroll
        for (int ks = 0; ks < 4; ++ks) {
          const unsigned short* bs = (ks < 2) ? XF : H0F[prv];
          bf16x8 bf = *(const bf16x8*)(bs + (((ks & 1) * 4 + nt) * 64 + l) * 8);
          acc[0][nt2] = __builtin_amdgcn_mfma_f32_16x16x32_bf16(afr[0][0][ks], bf, acc[0][nt2], 0, 0, 0);
          acc[1][nt2] = __builtin_amdgcn_mfma_f32_16x16x32_bf16(afr[0][1][ks], bf, acc[1][nt2], 0, 0, 0);
        }
      }
      // ---- activation 0 (in-register) -> H0F[cur]
      #pragma unroll
      for (int mt2 = 0; mt2 < 2; ++mt2)
        #pragma unroll
        for (int nt2 = 0; nt2 < 2; ++nt2) {
          int nt = 2 * ntp + nt2;
          f32x4 g = acc[mt2][nt2];
          float ig = sigf(g[0]);
          float fg = sigf(g[1]);
          float gg = tanh_f(g[2]);
          float og = sigf(g[3]);
          float c = fg * c0a[mt2][nt2] + ig * gg;
          c0a[mt2][nt2] = c;
          H0F[cur][hbase[mt2] + nt * 512] = f2bf(og * tanh_f(c));
        }
    }
    __syncthreads();

    // ---- layer 1: MFMA (reads H0F[cur], H1F[prv])
    {
      f32x4 acc[2][2];
      #pragma unroll
      for (int mt2 = 0; mt2 < 2; ++mt2)
        #pragma unroll
        for (int nt2 = 0; nt2 < 2; ++nt2) {
          float4 bv = bias1[mt2];
          acc[mt2][nt2] = (f32x4){bv.x, bv.y, bv.z, bv.w};
        }
      #pragma unroll
      for (int nt2 = 0; nt2 < 2; ++nt2) {
        int nt = 2 * ntp + nt2;
        #pragma unroll
        for (int ks = 0; ks < 4; ++ks) {
          const unsigned short* bs = (ks < 2) ? H0F[cur] : H1F[prv];
          bf16x8 bf = *(const bf16x8*)(bs + (((ks & 1) * 4 + nt) * 64 + l) * 8);
          acc[0][nt2] = __builtin_amdgcn_mfma_f32_16x16x32_bf16(afr[1][0][ks], bf, acc[0][nt2], 0, 0, 0);
          acc[1][nt2] = __builtin_amdgcn_mfma_f32_16x16x32_bf16(afr[1][1][ks], bf, acc[1][nt2], 0, 0, 0);
        }
      }
      // ---- activation 1 -> H1F[cur] + OUTB
      #pragma unroll
      for (int mt2 = 0; mt2 < 2; ++mt2)
        #pragma unroll
        for (int nt2 = 0; nt2 < 2; ++nt2) {
          int nt = 2 * ntp + nt2;
          f32x4 g = acc[mt2][nt2];
          float ig = sigf(g[0]);
          float fg = sigf(g[1]);
          float gg = tanh_f(g[2]);
          float og = sigf(g[3]);
          float c = fg * c1a[mt2][nt2] + ig * gg;
          c1a[mt2][nt2] = c;
          unsigned short hb = f2bf(og * tanh_f(c));
          H1F[cur][hbase[mt2] + nt * 512] = hb;
          OUTB[obase[mt2] + nt * 1088] = hb;
        }
    }
    __syncthreads();

    // ---- coalesced h1 -> global x2
    {
      uint2 ov = *(const uint2*)(OUTB + outsrc);
      *(uint2*)(x2g + t * 64) = ov;
    }
  }
}

// ---------- K7: attention (folded) + MLP ----------
__global__ __launch_bounds__(256) void k_attn(const unsigned short* __restrict__ x2,
    const float* __restrict__ wp, const float* __restrict__ aw,
    const float* __restrict__ obv, const float* __restrict__ pb1,
    const float* __restrict__ pb2, const float* __restrict__ pb3,
    float* __restrict__ outp) {
  __shared__ float smem[8192];
  int lane = threadIdx.x & 63;
  float* W = smem + ((threadIdx.x >> 6) << 11);
  int m = (blockIdx.x << 2) + (threadIdx.x >> 6);
  const uint4* xp = (const uint4*)(x2 + (size_t)m * 1024);
  #pragma unroll
  for (int u = 0; u < 2; ++u) {
    uint4 pv = xp[lane * 2 + u];
    int f0 = (lane * 2 + u) * 8;
    unsigned int ww[4] = {pv.x, pv.y, pv.z, pv.w};
    #pragma unroll
    for (int j = 0; j < 4; ++j) {
      int f = f0 + j * 2;
      int t = f >> 6, ch = f & 63;
      W[t * 65 + ch]     = bf2f((unsigned short)(ww[j] & 0xffff));
      W[t * 65 + ch + 1] = bf2f((unsigned short)(ww[j] >> 16));
    }
  }
  __syncthreads();
  {
    float qacc = wp[O_QB + lane];
    const float* aqT = wp + O_AQT;
    #pragma unroll 4
    for (int kk = 0; kk < 64; ++kk) qacc += aqT[kk * 64 + lane] * W[15 * 65 + kk];
    W[1040 + lane] = qacc;
  }
  __syncthreads();
  #pragma unroll
  for (int h = 0; h < 4; ++h) {
    float a = 0.f;
    #pragma unroll 4
    for (int d = 0; d < 16; ++d) {
      float coef = W[1040 + h * 16 + d];
      a += aw[(64 + h * 16 + d) * 64 + lane] * coef;
    }
    W[1104 + h * 68 + lane] = a;
  }
  __syncthreads();
  {
    int hh = lane >> 4, tt2 = lane & 15;
    float sc = 0.f;
    #pragma unroll 4
    for (int ch = 0; ch < 64; ++ch)
      sc += W[1104 + hh * 68 + ch] * W[tt2 * 65 + ch];
    float mx = sc;
    mx = fmaxf(mx, __shfl_xor(mx, 1));
    mx = fmaxf(mx, __shfl_xor(mx, 2));
    mx = fmaxf(mx, __shfl_xor(mx, 4));
    mx = fmaxf(mx, __shfl_xor(mx, 8));
    float e = __expf(sc - mx);
    float sum = e;
    sum += __shfl_xor(sum, 1);
    sum += __shfl_xor(sum, 2);
    sum += __shfl_xor(sum, 4);
    sum += __shfl_xor(sum, 8);
    W[1376 + lane] = e / sum;
  }
  __syncthreads();
  {
    float hb[4] = {0.f, 0.f, 0.f, 0.f};
    for (int t = 0; t < 16; ++t) {
      float xv = W[t * 65 + lane];
      #pragma unroll
      for (int h = 0; h < 4; ++h) hb[h] += W[1376 + h * 16 + t] * xv;
    }
    #pragma unroll
    for (int h = 0; h < 4; ++h) W[1440 + h * 68 + lane] = hb[h];
  }
  __syncthreads();
  {
    const float* wvT = wp + O_WVT;
    float oacc = wp[O_VB + lane];
    int hsel = lane >> 4;
    #pragma unroll 4
    for (int k = 0; k < 64; ++k) oacc += wvT[k * 64 + lane] * W[1440 + hsel * 68 + k];
    W[1712 + lane] = oacc;
  }
  __syncthreads();
  {
    const float* owT = wp + O_OWT;
    float facc = obv[lane];
    #pragma unroll 4
    for (int k = 0; k < 64; ++k) facc += owT[k * 64 + lane] * W[1712 + k];
    W[1776 + lane] = facc;
  }
  __syncthreads();
  {
    const float* p1T = wp + O_P1T;
    float a0 = pb1[lane], a1 = pb1[64 + lane];
    #pragma unroll 4
    for (int k = 0; k < 64; ++k) {
      float fv = W[1776 + k];
      a0 += p1T[k * 128 + lane] * fv;
      a1 += p1T[k * 128 + 64 + lane] * fv;
    }
    W[1840 + lane] = fmaxf(a0, 0.f);
    W[1904 + lane] = fmaxf(a1, 0.f);
  }
  __syncthreads();
  {
    const float* p2T = wp + O_P2T;
    float a2 = pb2[lane];
    #pragma unroll 4
    for (int k = 0; k < 128; ++k) a2 += p2T[k * 64 + lane] * W[1840 + k];
    W[1968 + lane] = fmaxf(a2, 0.f);
  }
  __syncthreads();
  if (lane < 13) {
    const float* p3T = wp + O_P3T;
    float a3 = pb3[lane];
    #pragma unroll 4
    for (int k = 0; k < 64; ++k) a3 += p3T[k * 16 + lane] * W[1968 + k];
    outp[(size_t)m * 13 + lane] = a3;
  }
}

extern "C" void kernel_launch(void* const* d_in, const int* in_sizes, int n_in,
                              void* d_out, int out_size, void* d_ws, size_t ws_size,
                              hipStream_t stream) {
  (void)in_sizes; (void)n_in; (void)out_size; (void)ws_size;
  const float* nf   = (const float*)d_in[0];
  const int*   ei   = (const int*)d_in[1];
  const float* sw1  = (const float*)d_in[2];
  const float* sb1  = (const float*)d_in[3];
  const float* sw2  = (const float*)d_in[4];
  const float* sb2  = (const float*)d_in[5];
  const float* wih0 = (const float*)d_in[6];
  const float* whh0 = (const float*)d_in[7];
  const float* bih0 = (const float*)d_in[8];
  const float* bhh0 = (const float*)d_in[9];
  const float* wih1 = (const float*)d_in[10];
  const float* whh1 = (const float*)d_in[11];
  const float* bih1 = (const float*)d_in[12];
  const float* bhh1 = (const float*)d_in[13];
  const float* aw   = (const float*)d_in[14];
  const float* ab   = (const float*)d_in[15];
  const float* ow   = (const float*)d_in[16];
  const float* ob   = (const float*)d_in[17];
  const float* pw1  = (const float*)d_in[18];
  const float* pb1  = (const float*)d_in[19];
  const float* pw2  = (const float*)d_in[20];
  const float* pb2  = (const float*)d_in[21];
  const float* pw3  = (const float*)d_in[22];
  const float* pb3  = (const float*)d_in[23];

  char* ws = (char*)d_ws;
  float* wT = (float*)ws;                                   //   0 .. 384 KB
  unsigned short* WA = (unsigned short*)(ws + 393216);      // 384 KB (128 KB)
  int* cnt  = (int*)(ws + 524288);                          // 512 KB (256 KB)
  int* fill = (int*)(ws + 786432);                          // 768 KB (256 KB)
  int* rp   = (int*)(ws + 1048576);                         //   1 MB (~256 KB)
  int* col  = (int*)(ws + 1572864);                         // 1.5 MB (8 MB)
  unsigned short* henc = (unsigned short*)(ws + 10485760);  //  10 MB (32 MB)
  unsigned short* hmp  = (unsigned short*)(ws + 44040192);  //  42 MB (32 MB)
  unsigned short* x2   = henc;   // alias: henc dead after k_mp
  float* outp = (float*)d_out;

  hipMemsetAsync(ws + 524288, 0, 524288, stream);
  k_prep<<<64, 256, 0, stream>>>(wih0, whh0, bih0, bhh0, wih1, whh1, bih1, bhh1, wT);
  k_prep_wa<<<256, 256, 0, stream>>>(wih0, whh0, wih1, whh1, WA);
  k_prep2<<<32, 256, 0, stream>>>(aw, ab, ow, pw1, pw2, pw3, wT);
  k_enc<<<1024, 256, 0, stream>>>(nf, sw1, sb1, sw2, sb2, henc);
  k_count<<<8192, 256, 0, stream>>>(ei, cnt);
  k_scan<<<16, 256, 0, stream>>>(cnt, rp);
  k_scatter<<<8192, 256, 0, stream>>>(ei, rp, fill, col);
  k_mp<<<16384, 256, 0, stream>>>(henc, rp, col, hmp);
  k_lstm<<<256, 1024, 0, stream>>>(hmp, WA, wT, x2);
  k_attn<<<4096, 256, 0, stream>>>(x2, wT, aw, ob, pb1, pb2, pb3, outp);
}